// Round 12
// baseline (520.758 us; speedup 1.0000x reference)
//
#include <hip/hip_runtime.h>

#define N_NODES 50000
#define N_EDGES 800000
#define N_GRAPHS 256
#define DIN 126
#define H 128
#define MP 50048           // N_NODES padded to 128
#define NB_SCAN 196        // ceil(N_NODES/256)

typedef __attribute__((ext_vector_type(8))) _Float16 half8v;
typedef __attribute__((ext_vector_type(4))) float f32x4;

// ---------------------------------------------------------------------------
// A conversion (layer-1 input only): X fp32 [M,Kd] -> A16 fp16 [MP][128]
// Writes ALL MP rows (zero pads stay clean for every layer).
// ---------------------------------------------------------------------------
__global__ __launch_bounds__(256) void conv_A(const float* __restrict__ X, int M, int Kd,
                                              _Float16* __restrict__ A16)
{
    const int t = blockIdx.x * 256 + threadIdx.x;
    const int row = t >> 4;
    if (row >= MP) return;
    const int k0 = (t & 15) * 8;
    half8v v8;
    #pragma unroll
    for (int j = 0; j < 8; ++j) {
        const int k = k0 + j;
        float v = 0.f;
        if (row < M && k < Kd) v = X[(size_t)row * Kd + k];
        v8[j] = (_Float16)v;
    }
    *(half8v*)&A16[(size_t)row * 128 + k0] = v8;
}

// ---------------------------------------------------------------------------
// W conversion, all 3 layers in one launch: 12 x [Kd,128] fp32 ->
// transposed Wt16 fp16 [3][512 n][128 k], zero-padded past Kd.
// ---------------------------------------------------------------------------
struct WPtrs { const float* w[12]; };

__global__ __launch_bounds__(256) void conv_W3(WPtrs P, _Float16* __restrict__ Wt16)
{
    const int t = blockIdx.x * 256 + threadIdx.x;
    if (t >= 3 * 512 * 128) return;
    const int layer = t >> 16;
    const int r = t & 65535;
    const int n = r >> 7, k = r & 127;
    const int mtx = n >> 7, cc = n & 127;
    const int Kd = (layer == 0) ? DIN : H;
    const float* W = P.w[layer * 4 + mtx];
    const float v = (k < Kd) ? W[(size_t)k * 128 + cc] : 0.f;
    Wt16[t] = (_Float16)v;
}

// ---------------------------------------------------------------------------
// MFMA GEMM v7: single fp16 (16x16x32_f16) -- no hi/lo split.  R11 structure:
// block = 64 A-rows x 2 weight matrices (blockIdx.y), A staged once in 16KB
// LDS (row stride 128B, slot=(k&7)^(r&7): 0 bank conflicts), W from global
// (L2-hot), one barrier, epilogue branch hoisted outside the store nests.
// Outputs: EK=exp(-K) fp32, EQ=exp(-Q) fp16, V fp16, S fp32.
// ---------------------------------------------------------------------------
__global__ __launch_bounds__(256, 5) void gemm_mfma(
    const _Float16* __restrict__ A16, const _Float16* __restrict__ Wt16,
    const float* __restrict__ bias0, const float* __restrict__ bias1,
    const float* __restrict__ bias2, const float* __restrict__ bias3,
    float* __restrict__ OEK, _Float16* __restrict__ OEQ,
    _Float16* __restrict__ OV, float* __restrict__ OS, int M)
{
    __shared__ _Float16 ldsA[2][64 * 64];  // [k-half][row*64 + slot*8], 16KB
    const int t = threadIdx.x;
    const int l = t & 63, wc = t >> 6;
    const int row0 = blockIdx.x * 64;
    const int mp = blockIdx.y;             // matrix pair: {0,1} or {2,3}
    const int fr = l & 15;
    const int kq = l >> 4;

    // ---- stage A: 1024 granules of 16B, 4 per thread
    #pragma unroll
    for (int i = 0; i < 4; ++i) {
        const int gi = i * 256 + t;        // 0..1023
        const int kh = gi >> 9;
        const int r = (gi >> 3) & 63;
        const int j = gi & 7;
        const int slot = j ^ (r & 7);
        *(half8v*)&ldsA[kh][r * 64 + slot * 8] =
            *(const half8v*)&A16[(size_t)(row0 + r) * 128 + kh * 64 + j * 8];
    }
    __syncthreads();   // the only barrier

    #pragma unroll
    for (int mi = 0; mi < 2; ++mi) {
        const int mtx = mp * 2 + mi;
        f32x4 acc[4][2] = {};
        #pragma unroll
        for (int step = 0; step < 4; ++step) {
            const int kg = step * 4 + kq;
            const int kh = kg >> 3, kk = kg & 7;
            half8v a[4];
            #pragma unroll
            for (int m = 0; m < 4; ++m) {
                const int ar = m * 16 + fr;
                const int slot = kk ^ (ar & 7);
                a[m] = *(const half8v*)&ldsA[kh][ar * 64 + slot * 8];
            }
            half8v w[2];
            #pragma unroll
            for (int n = 0; n < 2; ++n) {
                const size_t wo = (size_t)(mtx * 128 + wc * 32 + n * 16 + fr) * 128 + kg * 8;
                w[n] = *(const half8v*)&Wt16[wo];
            }
            #pragma unroll
            for (int m = 0; m < 4; ++m)
                #pragma unroll
                for (int n = 0; n < 2; ++n)
                    acc[m][n] = __builtin_amdgcn_mfma_f32_16x16x32_f16(a[m], w[n], acc[m][n], 0, 0, 0);
        }
        // ---- epilogue: branch hoisted outside the store nests
        const float* bias = (mtx == 0) ? bias0 : (mtx == 1) ? bias1
                          : (mtx == 2) ? bias2 : bias3;
        if (mtx == 0) {
            #pragma unroll
            for (int n = 0; n < 2; ++n) {
                const int col = wc * 32 + n * 16 + fr;
                const float bv = bias[col];
                #pragma unroll
                for (int m = 0; m < 4; ++m) {
                    const int rb = row0 + m * 16 + kq * 4;
                    #pragma unroll
                    for (int j = 0; j < 4; ++j) {
                        const int r = rb + j;
                        if (r < M) OEK[(size_t)r * 128 + col] = __expf(-(acc[m][n][j] + bv));
                    }
                }
            }
        } else if (mtx == 1) {
            #pragma unroll
            for (int n = 0; n < 2; ++n) {
                const int col = wc * 32 + n * 16 + fr;
                const float bv = bias[col];
                #pragma unroll
                for (int m = 0; m < 4; ++m) {
                    const int rb = row0 + m * 16 + kq * 4;
                    #pragma unroll
                    for (int j = 0; j < 4; ++j) {
                        const int r = rb + j;
                        if (r < M) OEQ[(size_t)r * 128 + col] = (_Float16)__expf(-(acc[m][n][j] + bv));
                    }
                }
            }
        } else if (mtx == 2) {
            #pragma unroll
            for (int n = 0; n < 2; ++n) {
                const int col = wc * 32 + n * 16 + fr;
                const float bv = bias[col];
                #pragma unroll
                for (int m = 0; m < 4; ++m) {
                    const int rb = row0 + m * 16 + kq * 4;
                    #pragma unroll
                    for (int j = 0; j < 4; ++j) {
                        const int r = rb + j;
                        if (r < M) OV[(size_t)r * 128 + col] = (_Float16)(acc[m][n][j] + bv);
                    }
                }
            }
        } else {
            #pragma unroll
            for (int n = 0; n < 2; ++n) {
                const int col = wc * 32 + n * 16 + fr;
                const float bv = bias[col];
                #pragma unroll
                for (int m = 0; m < 4; ++m) {
                    const int rb = row0 + m * 16 + kq * 4;
                    #pragma unroll
                    for (int j = 0; j < 4; ++j) {
                        const int r = rb + j;
                        if (r < M) OS[(size_t)r * 128 + col] = acc[m][n][j] + bv;
                    }
                }
            }
        }
    }
}

// ---------------------------------------------------------------------------
// CSR build (unchanged)
// ---------------------------------------------------------------------------
__global__ __launch_bounds__(256) void hist_kernel(const int* __restrict__ ei,
                                                   int* __restrict__ cnt, int E)
{
    const int e = blockIdx.x * 256 + threadIdx.x;
    if (e < E) atomicAdd(&cnt[ei[E + e]], 1);
}

__global__ __launch_bounds__(256) void scan_p1(const int* __restrict__ cnt,
                                               int* __restrict__ bsum, int Nn)
{
    __shared__ int red[256];
    const int t = threadIdx.x;
    const int i = blockIdx.x * 256 + t;
    red[t] = (i < Nn) ? cnt[i] : 0;
    __syncthreads();
    for (int d = 128; d > 0; d >>= 1) {
        if (t < d) red[t] += red[t + d];
        __syncthreads();
    }
    if (t == 0) bsum[blockIdx.x] = red[0];
}

__global__ __launch_bounds__(256) void scan_p2(const int* __restrict__ bsum,
                                               int* __restrict__ bsoff,
                                               int* __restrict__ off, int Nn)
{
    __shared__ int sc[256];
    const int t = threadIdx.x;
    const int v = (t < NB_SCAN) ? bsum[t] : 0;
    sc[t] = v;
    __syncthreads();
    #pragma unroll
    for (int d = 1; d < 256; d <<= 1) {
        const int a = (t >= d) ? sc[t - d] : 0;
        __syncthreads();
        sc[t] += a;
        __syncthreads();
    }
    if (t < NB_SCAN) bsoff[t] = sc[t] - v;
    if (t == NB_SCAN - 1) off[Nn] = sc[t];
}

__global__ __launch_bounds__(256) void scan_p3(int* __restrict__ cnt,
                                               const int* __restrict__ bsoff,
                                               int* __restrict__ off, int Nn)
{
    __shared__ int sc[256];
    const int t = threadIdx.x;
    const int i = blockIdx.x * 256 + t;
    const int v = (i < Nn) ? cnt[i] : 0;
    sc[t] = v;
    __syncthreads();
    #pragma unroll
    for (int d = 1; d < 256; d <<= 1) {
        const int a = (t >= d) ? sc[t - d] : 0;
        __syncthreads();
        sc[t] += a;
        __syncthreads();
    }
    if (i < Nn) {
        const int o = bsoff[blockIdx.x] + sc[t] - v;
        off[i] = o;
        cnt[i] = o;
    }
}

__global__ __launch_bounds__(256) void scatter_kernel(const int* __restrict__ ei,
                                                      int* __restrict__ cur,
                                                      int* __restrict__ csr_src, int E)
{
    const int e = blockIdx.x * 256 + threadIdx.x;
    if (e >= E) return;
    const int s = ei[e];
    const int d = ei[E + e];
    const int pos = atomicAdd(&cur[d], 1);
    csr_src[pos] = s;
}

// ---------------------------------------------------------------------------
// CSR aggregation: gate = rcp(1 + ek*eq), fp16 gathers, 16 lanes/edge.
// FUSE=1: epilogue writes next layer's fp16 A (relu fused).
// FUSE=0: writes fp32 h for the pool.
// ---------------------------------------------------------------------------
template<int FUSE>
__global__ __launch_bounds__(256) void agg_csr(
    const float* __restrict__ EKb, const _Float16* __restrict__ EQ16,
    const _Float16* __restrict__ V16, const int* __restrict__ off,
    const int* __restrict__ csr_src, float* __restrict__ hSkip,
    _Float16* __restrict__ A16, int Nn)
{
    const int node = blockIdx.x * 4 + (threadIdx.x >> 6);
    if (node >= Nn) return;
    const int lane = threadIdx.x & 63;
    const int grp = lane >> 4;
    const int sub = lane & 15;
    const int q = sub * 8;

    const float4 kA = *(const float4*)(EKb + (size_t)node * H + q);
    const float4 kB = *(const float4*)(EKb + (size_t)node * H + q + 4);
    float acc[8] = {};

    const int begin = off[node], end = off[node + 1];
    for (int j0 = begin; j0 < end; j0 += 64) {
        const int nrem = end - j0;
        const int nk = nrem < 64 ? nrem : 64;
        const int sv = (lane < nk) ? csr_src[j0 + lane] : 0;
        #pragma unroll 2
        for (int k = 0; k < nk; k += 4) {
            const int myk = k + grp;
            const int s = __shfl(sv, myk < nk ? myk : 0);
            if (myk < nk) {
                const half8v qv = *(const half8v*)(EQ16 + (size_t)s * H + q);
                const half8v vv = *(const half8v*)(V16 + (size_t)s * H + q);
                acc[0] = fmaf((float)vv[0], __builtin_amdgcn_rcpf(fmaf(kA.x, (float)qv[0], 1.f)), acc[0]);
                acc[1] = fmaf((float)vv[1], __builtin_amdgcn_rcpf(fmaf(kA.y, (float)qv[1], 1.f)), acc[1]);
                acc[2] = fmaf((float)vv[2], __builtin_amdgcn_rcpf(fmaf(kA.z, (float)qv[2], 1.f)), acc[2]);
                acc[3] = fmaf((float)vv[3], __builtin_amdgcn_rcpf(fmaf(kA.w, (float)qv[3], 1.f)), acc[3]);
                acc[4] = fmaf((float)vv[4], __builtin_amdgcn_rcpf(fmaf(kB.x, (float)qv[4], 1.f)), acc[4]);
                acc[5] = fmaf((float)vv[5], __builtin_amdgcn_rcpf(fmaf(kB.y, (float)qv[5], 1.f)), acc[5]);
                acc[6] = fmaf((float)vv[6], __builtin_amdgcn_rcpf(fmaf(kB.z, (float)qv[6], 1.f)), acc[6]);
                acc[7] = fmaf((float)vv[7], __builtin_amdgcn_rcpf(fmaf(kB.w, (float)qv[7], 1.f)), acc[7]);
            }
        }
    }
    #pragma unroll
    for (int i = 0; i < 8; ++i) {
        acc[i] += __shfl_xor(acc[i], 16);
        acc[i] += __shfl_xor(acc[i], 32);
    }
    if (grp == 0) {
        const float* sk = hSkip + (size_t)node * H + q;
        const float4 eA = *(const float4*)sk;
        const float4 eB = *(const float4*)(sk + 4);
        float h[8];
        h[0] = eA.x + acc[0]; h[1] = eA.y + acc[1];
        h[2] = eA.z + acc[2]; h[3] = eA.w + acc[3];
        h[4] = eB.x + acc[4]; h[5] = eB.y + acc[5];
        h[6] = eB.z + acc[6]; h[7] = eB.w + acc[7];
        if (FUSE) {
            half8v hv;
            #pragma unroll
            for (int j = 0; j < 8; ++j)
                hv[j] = (_Float16)fmaxf(h[j], 0.f);
            *(half8v*)&A16[(size_t)node * 128 + q] = hv;
        } else {
            float* o = hSkip + (size_t)node * H + q;
            *(float4*)o = make_float4(h[0], h[1], h[2], h[3]);
            *(float4*)(o + 4) = make_float4(h[4], h[5], h[6], h[7]);
        }
    }
}

// ---------------------------------------------------------------------------
// Pool + MLP (unchanged)
// ---------------------------------------------------------------------------
__global__ __launch_bounds__(256) void gstart_kernel(const int* __restrict__ batch,
                                                     int* __restrict__ gstart, int Nn)
{
    const int n = blockIdx.x * 256 + threadIdx.x;
    if (n >= Nn) return;
    const int b = batch[n];
    const int bp = (n == 0) ? -1 : batch[n - 1];
    for (int g = bp + 1; g <= b; ++g) gstart[g] = n;
    if (n == Nn - 1)
        for (int g = b + 1; g <= N_GRAPHS; ++g) gstart[g] = Nn;
}

__global__ __launch_bounds__(128) void pool_seg(const float* __restrict__ h,
                                                const int* __restrict__ gstart,
                                                float* __restrict__ hg)
{
    const int g = blockIdx.x;
    const int part = blockIdx.y;
    const int t = threadIdx.x;
    const int b0 = gstart[g], b1 = gstart[g + 1];
    float acc = 0.f;
    for (int n = b0 + part; n < b1; n += 4) acc += h[(size_t)n * H + t];
    atomicAdd(&hg[(size_t)g * H + t], acc);
}

__global__ __launch_bounds__(64) void mlp_kernel(
    const float* __restrict__ hg,
    const float* __restrict__ W4, const float* __restrict__ b4,
    const float* __restrict__ W5, const float* __restrict__ b5,
    float* __restrict__ out)
{
    const int g = blockIdx.x;
    const int c = threadIdx.x;
    __shared__ float hrow[H];
    for (int k = c; k < H; k += 64) hrow[k] = hg[(size_t)g * H + k];
    __syncthreads();
    float s = b4[c];
    #pragma unroll 8
    for (int k = 0; k < H; ++k) s += hrow[k] * W4[(size_t)k * 64 + c];
    s = fmaxf(s, 0.f) * W5[c];
    #pragma unroll
    for (int off = 32; off > 0; off >>= 1) s += __shfl_down(s, off);
    if (c == 0) out[g] = 1.f / (1.f + __expf(-(s + b5[0])));
}

// ---------------------------------------------------------------------------
extern "C" void kernel_launch(void* const* d_in, const int* in_sizes, int n_in,
                              void* d_out, int out_size, void* d_ws, size_t ws_size,
                              hipStream_t stream)
{
    const float* x = (const float*)d_in[0];
    const float *Wk[3], *bk[3], *Wq[3], *bq[3], *Wv[3], *bv[3], *Wsk[3], *bs[3];
    for (int l = 0; l < 3; ++l) {
        const int base = 2 + l * 8;
        Wk[l]  = (const float*)d_in[base + 0]; bk[l] = (const float*)d_in[base + 1];
        Wq[l]  = (const float*)d_in[base + 2]; bq[l] = (const float*)d_in[base + 3];
        Wv[l]  = (const float*)d_in[base + 4]; bv[l] = (const float*)d_in[base + 5];
        Wsk[l] = (const float*)d_in[base + 6]; bs[l] = (const float*)d_in[base + 7];
    }
    const float* W4 = (const float*)d_in[26];
    const float* b4 = (const float*)d_in[27];
    const float* W5 = (const float*)d_in[28];
    const float* b5 = (const float*)d_in[29];
    const int* ei    = (const int*)d_in[30];
    const int* batch = (const int*)d_in[31];
    float* out = (float*)d_out;

    const size_t NH = (size_t)N_NODES * H;
    const size_t AH = (size_t)MP * 128;
    const size_t WH3 = (size_t)3 * 512 * 128;
    float*     EKb  = (float*)d_ws;
    float*     hbuf = EKb + NH;
    _Float16*  EQ16 = (_Float16*)(hbuf + NH);
    _Float16*  V16  = EQ16 + NH;
    _Float16*  A16  = V16 + NH;
    _Float16*  Wt16 = A16 + AH;
    float*     hg   = (float*)(Wt16 + WH3);               // G*H (zeroed)
    int*       off  = (int*)(hg + (size_t)N_GRAPHS * H);  // N+1 (zeroed)
    int*       cnt  = off + (N_NODES + 1);                // N   (zeroed)
    int*       csr  = cnt + N_NODES;                      // E
    int*       gst  = csr + N_EDGES;                      // G+1
    int*       bsum = gst + (N_GRAPHS + 1);               // 256
    int*       bsoff= bsum + 256;                         // 256
    const size_t need = (2 * NH + (size_t)N_GRAPHS * H) * sizeof(float)
                      + (2 * NH + AH + WH3) * sizeof(_Float16)
                      + (size_t)(2 * N_NODES + 1 + N_EDGES + N_GRAPHS + 1 + 512) * sizeof(int);
    if (ws_size < need) return;

    const int eblk = (N_EDGES + 255) / 256;
    const int ablk = (N_NODES + 3) / 4;
    const int nblk = (N_NODES + 255) / 256;
    const int cablk = (MP * 16) / 256;
    const dim3 ggrid(MP / 64, 2);        // 782 x 2 = 1564 blocks
    const dim3 pgrid(N_GRAPHS, 4);

    // ---- one fused memset: hg (pool accum) + off + cnt (contiguous)
    hipMemsetAsync(hg, 0,
        ((size_t)N_GRAPHS * H + 2 * N_NODES + 1) * sizeof(int), stream);

    // ---- CSR + graph segments + weight conversion (reused across layers)
    hist_kernel<<<eblk, 256, 0, stream>>>(ei, cnt, N_EDGES);
    scan_p1<<<NB_SCAN, 256, 0, stream>>>(cnt, bsum, N_NODES);
    scan_p2<<<1, 256, 0, stream>>>(bsum, bsoff, off, N_NODES);
    scan_p3<<<NB_SCAN, 256, 0, stream>>>(cnt, bsoff, off, N_NODES);
    scatter_kernel<<<eblk, 256, 0, stream>>>(ei, cnt, csr, N_EDGES);
    gstart_kernel<<<nblk, 256, 0, stream>>>(batch, gst, N_NODES);
    WPtrs wp;
    for (int l = 0; l < 3; ++l) {
        wp.w[l * 4 + 0] = Wk[l];
        wp.w[l * 4 + 1] = Wq[l];
        wp.w[l * 4 + 2] = Wv[l];
        wp.w[l * 4 + 3] = Wsk[l];
    }
    conv_W3<<<768, 256, 0, stream>>>(wp, Wt16);

    // ---- Layer 1
    conv_A<<<cablk, 256, 0, stream>>>(x, N_NODES, DIN, A16);
    gemm_mfma<<<ggrid, 256, 0, stream>>>(A16, Wt16,
        bk[0], bq[0], bv[0], bs[0], EKb, EQ16, V16, hbuf, N_NODES);
    agg_csr<1><<<ablk, 256, 0, stream>>>(EKb, EQ16, V16, off, csr, hbuf, A16, N_NODES);

    // ---- Layer 2
    gemm_mfma<<<ggrid, 256, 0, stream>>>(A16, Wt16 + 512 * 128,
        bk[1], bq[1], bv[1], bs[1], EKb, EQ16, V16, hbuf, N_NODES);
    agg_csr<1><<<ablk, 256, 0, stream>>>(EKb, EQ16, V16, off, csr, hbuf, A16, N_NODES);

    // ---- Layer 3
    gemm_mfma<<<ggrid, 256, 0, stream>>>(A16, Wt16 + 1024 * 128,
        bk[2], bq[2], bv[2], bs[2], EKb, EQ16, V16, hbuf, N_NODES);
    agg_csr<0><<<ablk, 256, 0, stream>>>(EKb, EQ16, V16, off, csr, hbuf, A16, N_NODES);

    // ---- Pool + MLP
    pool_seg<<<pgrid, 128, 0, stream>>>(hbuf, gst, hg);
    mlp_kernel<<<N_GRAPHS, 64, 0, stream>>>(hg, W4, b4, W5, b5, out);
}

// Round 13
// 467.767 us; speedup vs baseline: 1.1133x; 1.1133x over previous
//
#include <hip/hip_runtime.h>

#define N_NODES 50000
#define N_EDGES 800000
#define N_GRAPHS 256
#define DIN 126
#define H 128
#define MP 50048           // N_NODES padded to 128
#define NB_SCAN 196        // ceil(N_NODES/256)

typedef __attribute__((ext_vector_type(8))) _Float16 half8v;
typedef __attribute__((ext_vector_type(4))) _Float16 half4v;
typedef __attribute__((ext_vector_type(4))) float f32x4;

// ---------------------------------------------------------------------------
// A conversion (layer-1 input only): X fp32 [M,Kd] -> A16 fp16 [MP][128]
// ---------------------------------------------------------------------------
__global__ __launch_bounds__(256) void conv_A(const float* __restrict__ X, int M, int Kd,
                                              _Float16* __restrict__ A16)
{
    const int t = blockIdx.x * 256 + threadIdx.x;
    const int row = t >> 4;
    if (row >= MP) return;
    const int k0 = (t & 15) * 8;
    half8v v8;
    #pragma unroll
    for (int j = 0; j < 8; ++j) {
        const int k = k0 + j;
        float v = 0.f;
        if (row < M && k < Kd) v = X[(size_t)row * Kd + k];
        v8[j] = (_Float16)v;
    }
    *(half8v*)&A16[(size_t)row * 128 + k0] = v8;
}

// ---------------------------------------------------------------------------
// W conversion, all 3 layers in one launch.
// ---------------------------------------------------------------------------
struct WPtrs { const float* w[12]; };

__global__ __launch_bounds__(256) void conv_W3(WPtrs P, _Float16* __restrict__ Wt16)
{
    const int t = blockIdx.x * 256 + threadIdx.x;
    if (t >= 3 * 512 * 128) return;
    const int layer = t >> 16;
    const int r = t & 65535;
    const int n = r >> 7, k = r & 127;
    const int mtx = n >> 7, cc = n & 127;
    const int Kd = (layer == 0) ? DIN : H;
    const float* W = P.w[layer * 4 + mtx];
    const float v = (k < Kd) ? W[(size_t)k * 128 + cc] : 0.f;
    Wt16[t] = (_Float16)v;
}

// ---------------------------------------------------------------------------
// MFMA GEMM v8: fp16 single-MFMA with SWAPPED operands -- mfma(w, a, acc)
// computes D^T, so each lane holds ONE node-row and 4 CONSECUTIVE feature
// cols -> vectorized float4/half4 stores (R12's scalar column-scatter caused
// RMW write amplification: WRITE 148MB vs 77MB logical).  A staged once in
// 16KB LDS (slot=(k&7)^(r&7), 0 conflicts), W from global (L2-hot), one
// barrier.  Outputs: EK=exp(-K) fp32, EQ=exp(-Q) fp16, V fp16, S fp32.
// ---------------------------------------------------------------------------
__global__ __launch_bounds__(256, 5) void gemm_mfma(
    const _Float16* __restrict__ A16, const _Float16* __restrict__ Wt16,
    const float* __restrict__ bias0, const float* __restrict__ bias1,
    const float* __restrict__ bias2, const float* __restrict__ bias3,
    float* __restrict__ OEK, _Float16* __restrict__ OEQ,
    _Float16* __restrict__ OV, float* __restrict__ OS, int M)
{
    __shared__ _Float16 ldsA[2][64 * 64];  // [k-half][row*64 + slot*8], 16KB
    const int t = threadIdx.x;
    const int l = t & 63, wc = t >> 6;
    const int row0 = blockIdx.x * 64;
    const int mp = blockIdx.y;             // matrix pair: {0,1} or {2,3}
    const int fr = l & 15;
    const int kq = l >> 4;

    // ---- stage A: 1024 granules of 16B, 4 per thread
    #pragma unroll
    for (int i = 0; i < 4; ++i) {
        const int gi = i * 256 + t;        // 0..1023
        const int kh = gi >> 9;
        const int r = (gi >> 3) & 63;
        const int j = gi & 7;
        const int slot = j ^ (r & 7);
        *(half8v*)&ldsA[kh][r * 64 + slot * 8] =
            *(const half8v*)&A16[(size_t)(row0 + r) * 128 + kh * 64 + j * 8];
    }
    __syncthreads();   // the only barrier

    #pragma unroll
    for (int mi = 0; mi < 2; ++mi) {
        const int mtx = mp * 2 + mi;
        f32x4 acc[4][2] = {};
        #pragma unroll
        for (int step = 0; step < 4; ++step) {
            const int kg = step * 4 + kq;
            const int kh = kg >> 3, kk = kg & 7;
            half8v a[4];
            #pragma unroll
            for (int m = 0; m < 4; ++m) {
                const int ar = m * 16 + fr;
                const int slot = kk ^ (ar & 7);
                a[m] = *(const half8v*)&ldsA[kh][ar * 64 + slot * 8];
            }
            half8v w[2];
            #pragma unroll
            for (int n = 0; n < 2; ++n) {
                const size_t wo = (size_t)(mtx * 128 + wc * 32 + n * 16 + fr) * 128 + kg * 8;
                w[n] = *(const half8v*)&Wt16[wo];
            }
            // swapped operands: D^T -- lane = one node-row, 4 consecutive cols
            #pragma unroll
            for (int m = 0; m < 4; ++m)
                #pragma unroll
                for (int n = 0; n < 2; ++n)
                    acc[m][n] = __builtin_amdgcn_mfma_f32_16x16x32_f16(w[n], a[m], acc[m][n], 0, 0, 0);
        }
        // ---- epilogue: lane writes row r = row0+m*16+fr, cols c0..c0+3
        const float* bias = (mtx == 0) ? bias0 : (mtx == 1) ? bias1
                          : (mtx == 2) ? bias2 : bias3;
        if (mtx == 0) {
            #pragma unroll
            for (int n = 0; n < 2; ++n) {
                const int c0 = wc * 32 + n * 16 + kq * 4;
                const float4 bv = *(const float4*)&bias[c0];
                #pragma unroll
                for (int m = 0; m < 4; ++m) {
                    const int r = row0 + m * 16 + fr;
                    if (r < M) {
                        float4 o;
                        o.x = __expf(-(acc[m][n][0] + bv.x));
                        o.y = __expf(-(acc[m][n][1] + bv.y));
                        o.z = __expf(-(acc[m][n][2] + bv.z));
                        o.w = __expf(-(acc[m][n][3] + bv.w));
                        *(float4*)&OEK[(size_t)r * 128 + c0] = o;
                    }
                }
            }
        } else if (mtx == 1) {
            #pragma unroll
            for (int n = 0; n < 2; ++n) {
                const int c0 = wc * 32 + n * 16 + kq * 4;
                const float4 bv = *(const float4*)&bias[c0];
                #pragma unroll
                for (int m = 0; m < 4; ++m) {
                    const int r = row0 + m * 16 + fr;
                    if (r < M) {
                        half4v o;
                        o[0] = (_Float16)__expf(-(acc[m][n][0] + bv.x));
                        o[1] = (_Float16)__expf(-(acc[m][n][1] + bv.y));
                        o[2] = (_Float16)__expf(-(acc[m][n][2] + bv.z));
                        o[3] = (_Float16)__expf(-(acc[m][n][3] + bv.w));
                        *(half4v*)&OEQ[(size_t)r * 128 + c0] = o;
                    }
                }
            }
        } else if (mtx == 2) {
            #pragma unroll
            for (int n = 0; n < 2; ++n) {
                const int c0 = wc * 32 + n * 16 + kq * 4;
                const float4 bv = *(const float4*)&bias[c0];
                #pragma unroll
                for (int m = 0; m < 4; ++m) {
                    const int r = row0 + m * 16 + fr;
                    if (r < M) {
                        half4v o;
                        o[0] = (_Float16)(acc[m][n][0] + bv.x);
                        o[1] = (_Float16)(acc[m][n][1] + bv.y);
                        o[2] = (_Float16)(acc[m][n][2] + bv.z);
                        o[3] = (_Float16)(acc[m][n][3] + bv.w);
                        *(half4v*)&OV[(size_t)r * 128 + c0] = o;
                    }
                }
            }
        } else {
            #pragma unroll
            for (int n = 0; n < 2; ++n) {
                const int c0 = wc * 32 + n * 16 + kq * 4;
                const float4 bv = *(const float4*)&bias[c0];
                #pragma unroll
                for (int m = 0; m < 4; ++m) {
                    const int r = row0 + m * 16 + fr;
                    if (r < M) {
                        float4 o;
                        o.x = acc[m][n][0] + bv.x;
                        o.y = acc[m][n][1] + bv.y;
                        o.z = acc[m][n][2] + bv.z;
                        o.w = acc[m][n][3] + bv.w;
                        *(float4*)&OS[(size_t)r * 128 + c0] = o;
                    }
                }
            }
        }
    }
}

// ---------------------------------------------------------------------------
// CSR build (unchanged)
// ---------------------------------------------------------------------------
__global__ __launch_bounds__(256) void hist_kernel(const int* __restrict__ ei,
                                                   int* __restrict__ cnt, int E)
{
    const int e = blockIdx.x * 256 + threadIdx.x;
    if (e < E) atomicAdd(&cnt[ei[E + e]], 1);
}

__global__ __launch_bounds__(256) void scan_p1(const int* __restrict__ cnt,
                                               int* __restrict__ bsum, int Nn)
{
    __shared__ int red[256];
    const int t = threadIdx.x;
    const int i = blockIdx.x * 256 + t;
    red[t] = (i < Nn) ? cnt[i] : 0;
    __syncthreads();
    for (int d = 128; d > 0; d >>= 1) {
        if (t < d) red[t] += red[t + d];
        __syncthreads();
    }
    if (t == 0) bsum[blockIdx.x] = red[0];
}

__global__ __launch_bounds__(256) void scan_p2(const int* __restrict__ bsum,
                                               int* __restrict__ bsoff,
                                               int* __restrict__ off, int Nn)
{
    __shared__ int sc[256];
    const int t = threadIdx.x;
    const int v = (t < NB_SCAN) ? bsum[t] : 0;
    sc[t] = v;
    __syncthreads();
    #pragma unroll
    for (int d = 1; d < 256; d <<= 1) {
        const int a = (t >= d) ? sc[t - d] : 0;
        __syncthreads();
        sc[t] += a;
        __syncthreads();
    }
    if (t < NB_SCAN) bsoff[t] = sc[t] - v;
    if (t == NB_SCAN - 1) off[Nn] = sc[t];
}

__global__ __launch_bounds__(256) void scan_p3(int* __restrict__ cnt,
                                               const int* __restrict__ bsoff,
                                               int* __restrict__ off, int Nn)
{
    __shared__ int sc[256];
    const int t = threadIdx.x;
    const int i = blockIdx.x * 256 + t;
    const int v = (i < Nn) ? cnt[i] : 0;
    sc[t] = v;
    __syncthreads();
    #pragma unroll
    for (int d = 1; d < 256; d <<= 1) {
        const int a = (t >= d) ? sc[t - d] : 0;
        __syncthreads();
        sc[t] += a;
        __syncthreads();
    }
    if (i < Nn) {
        const int o = bsoff[blockIdx.x] + sc[t] - v;
        off[i] = o;
        cnt[i] = o;
    }
}

__global__ __launch_bounds__(256) void scatter_kernel(const int* __restrict__ ei,
                                                      int* __restrict__ cur,
                                                      int* __restrict__ csr_src, int E)
{
    const int e = blockIdx.x * 256 + threadIdx.x;
    if (e >= E) return;
    const int s = ei[e];
    const int d = ei[E + e];
    const int pos = atomicAdd(&cur[d], 1);
    csr_src[pos] = s;
}

// ---------------------------------------------------------------------------
// CSR aggregation (unchanged from R12): gate = rcp(1 + ek*eq), fp16 gathers.
// ---------------------------------------------------------------------------
template<int FUSE>
__global__ __launch_bounds__(256) void agg_csr(
    const float* __restrict__ EKb, const _Float16* __restrict__ EQ16,
    const _Float16* __restrict__ V16, const int* __restrict__ off,
    const int* __restrict__ csr_src, float* __restrict__ hSkip,
    _Float16* __restrict__ A16, int Nn)
{
    const int node = blockIdx.x * 4 + (threadIdx.x >> 6);
    if (node >= Nn) return;
    const int lane = threadIdx.x & 63;
    const int grp = lane >> 4;
    const int sub = lane & 15;
    const int q = sub * 8;

    const float4 kA = *(const float4*)(EKb + (size_t)node * H + q);
    const float4 kB = *(const float4*)(EKb + (size_t)node * H + q + 4);
    float acc[8] = {};

    const int begin = off[node], end = off[node + 1];
    for (int j0 = begin; j0 < end; j0 += 64) {
        const int nrem = end - j0;
        const int nk = nrem < 64 ? nrem : 64;
        const int sv = (lane < nk) ? csr_src[j0 + lane] : 0;
        #pragma unroll 2
        for (int k = 0; k < nk; k += 4) {
            const int myk = k + grp;
            const int s = __shfl(sv, myk < nk ? myk : 0);
            if (myk < nk) {
                const half8v qv = *(const half8v*)(EQ16 + (size_t)s * H + q);
                const half8v vv = *(const half8v*)(V16 + (size_t)s * H + q);
                acc[0] = fmaf((float)vv[0], __builtin_amdgcn_rcpf(fmaf(kA.x, (float)qv[0], 1.f)), acc[0]);
                acc[1] = fmaf((float)vv[1], __builtin_amdgcn_rcpf(fmaf(kA.y, (float)qv[1], 1.f)), acc[1]);
                acc[2] = fmaf((float)vv[2], __builtin_amdgcn_rcpf(fmaf(kA.z, (float)qv[2], 1.f)), acc[2]);
                acc[3] = fmaf((float)vv[3], __builtin_amdgcn_rcpf(fmaf(kA.w, (float)qv[3], 1.f)), acc[3]);
                acc[4] = fmaf((float)vv[4], __builtin_amdgcn_rcpf(fmaf(kB.x, (float)qv[4], 1.f)), acc[4]);
                acc[5] = fmaf((float)vv[5], __builtin_amdgcn_rcpf(fmaf(kB.y, (float)qv[5], 1.f)), acc[5]);
                acc[6] = fmaf((float)vv[6], __builtin_amdgcn_rcpf(fmaf(kB.z, (float)qv[6], 1.f)), acc[6]);
                acc[7] = fmaf((float)vv[7], __builtin_amdgcn_rcpf(fmaf(kB.w, (float)qv[7], 1.f)), acc[7]);
            }
        }
    }
    #pragma unroll
    for (int i = 0; i < 8; ++i) {
        acc[i] += __shfl_xor(acc[i], 16);
        acc[i] += __shfl_xor(acc[i], 32);
    }
    if (grp == 0) {
        const float* sk = hSkip + (size_t)node * H + q;
        const float4 eA = *(const float4*)sk;
        const float4 eB = *(const float4*)(sk + 4);
        float h[8];
        h[0] = eA.x + acc[0]; h[1] = eA.y + acc[1];
        h[2] = eA.z + acc[2]; h[3] = eA.w + acc[3];
        h[4] = eB.x + acc[4]; h[5] = eB.y + acc[5];
        h[6] = eB.z + acc[6]; h[7] = eB.w + acc[7];
        if (FUSE) {
            half8v hv;
            #pragma unroll
            for (int j = 0; j < 8; ++j)
                hv[j] = (_Float16)fmaxf(h[j], 0.f);
            *(half8v*)&A16[(size_t)node * 128 + q] = hv;
        } else {
            float* o = hSkip + (size_t)node * H + q;
            *(float4*)o = make_float4(h[0], h[1], h[2], h[3]);
            *(float4*)(o + 4) = make_float4(h[4], h[5], h[6], h[7]);
        }
    }
}

// ---------------------------------------------------------------------------
// Pool + MLP (unchanged)
// ---------------------------------------------------------------------------
__global__ __launch_bounds__(256) void gstart_kernel(const int* __restrict__ batch,
                                                     int* __restrict__ gstart, int Nn)
{
    const int n = blockIdx.x * 256 + threadIdx.x;
    if (n >= Nn) return;
    const int b = batch[n];
    const int bp = (n == 0) ? -1 : batch[n - 1];
    for (int g = bp + 1; g <= b; ++g) gstart[g] = n;
    if (n == Nn - 1)
        for (int g = b + 1; g <= N_GRAPHS; ++g) gstart[g] = Nn;
}

__global__ __launch_bounds__(128) void pool_seg(const float* __restrict__ h,
                                                const int* __restrict__ gstart,
                                                float* __restrict__ hg)
{
    const int g = blockIdx.x;
    const int part = blockIdx.y;
    const int t = threadIdx.x;
    const int b0 = gstart[g], b1 = gstart[g + 1];
    float acc = 0.f;
    for (int n = b0 + part; n < b1; n += 4) acc += h[(size_t)n * H + t];
    atomicAdd(&hg[(size_t)g * H + t], acc);
}

__global__ __launch_bounds__(64) void mlp_kernel(
    const float* __restrict__ hg,
    const float* __restrict__ W4, const float* __restrict__ b4,
    const float* __restrict__ W5, const float* __restrict__ b5,
    float* __restrict__ out)
{
    const int g = blockIdx.x;
    const int c = threadIdx.x;
    __shared__ float hrow[H];
    for (int k = c; k < H; k += 64) hrow[k] = hg[(size_t)g * H + k];
    __syncthreads();
    float s = b4[c];
    #pragma unroll 8
    for (int k = 0; k < H; ++k) s += hrow[k] * W4[(size_t)k * 64 + c];
    s = fmaxf(s, 0.f) * W5[c];
    #pragma unroll
    for (int off = 32; off > 0; off >>= 1) s += __shfl_down(s, off);
    if (c == 0) out[g] = 1.f / (1.f + __expf(-(s + b5[0])));
}

// ---------------------------------------------------------------------------
extern "C" void kernel_launch(void* const* d_in, const int* in_sizes, int n_in,
                              void* d_out, int out_size, void* d_ws, size_t ws_size,
                              hipStream_t stream)
{
    const float* x = (const float*)d_in[0];
    const float *Wk[3], *bk[3], *Wq[3], *bq[3], *Wv[3], *bv[3], *Wsk[3], *bs[3];
    for (int l = 0; l < 3; ++l) {
        const int base = 2 + l * 8;
        Wk[l]  = (const float*)d_in[base + 0]; bk[l] = (const float*)d_in[base + 1];
        Wq[l]  = (const float*)d_in[base + 2]; bq[l] = (const float*)d_in[base + 3];
        Wv[l]  = (const float*)d_in[base + 4]; bv[l] = (const float*)d_in[base + 5];
        Wsk[l] = (const float*)d_in[base + 6]; bs[l] = (const float*)d_in[base + 7];
    }
    const float* W4 = (const float*)d_in[26];
    const float* b4 = (const float*)d_in[27];
    const float* W5 = (const float*)d_in[28];
    const float* b5 = (const float*)d_in[29];
    const int* ei    = (const int*)d_in[30];
    const int* batch = (const int*)d_in[31];
    float* out = (float*)d_out;

    const size_t NH = (size_t)N_NODES * H;
    const size_t AH = (size_t)MP * 128;
    const size_t WH3 = (size_t)3 * 512 * 128;
    float*     EKb  = (float*)d_ws;
    float*     hbuf = EKb + NH;
    _Float16*  EQ16 = (_Float16*)(hbuf + NH);
    _Float16*  V16  = EQ16 + NH;
    _Float16*  A16  = V16 + NH;
    _Float16*  Wt16 = A16 + AH;
    float*     hg   = (float*)(Wt16 + WH3);               // G*H (zeroed)
    int*       off  = (int*)(hg + (size_t)N_GRAPHS * H);  // N+1 (zeroed)
    int*       cnt  = off + (N_NODES + 1);                // N   (zeroed)
    int*       csr  = cnt + N_NODES;                      // E
    int*       gst  = csr + N_EDGES;                      // G+1
    int*       bsum = gst + (N_GRAPHS + 1);               // 256
    int*       bsoff= bsum + 256;                         // 256
    const size_t need = (2 * NH + (size_t)N_GRAPHS * H) * sizeof(float)
                      + (2 * NH + AH + WH3) * sizeof(_Float16)
                      + (size_t)(2 * N_NODES + 1 + N_EDGES + N_GRAPHS + 1 + 512) * sizeof(int);
    if (ws_size < need) return;

    const int eblk = (N_EDGES + 255) / 256;
    const int ablk = (N_NODES + 3) / 4;
    const int nblk = (N_NODES + 255) / 256;
    const int cablk = (MP * 16) / 256;
    const dim3 ggrid(MP / 64, 2);        // 782 x 2 = 1564 blocks
    const dim3 pgrid(N_GRAPHS, 4);

    // ---- one fused memset: hg (pool accum) + off + cnt (contiguous)
    hipMemsetAsync(hg, 0,
        ((size_t)N_GRAPHS * H + 2 * N_NODES + 1) * sizeof(int), stream);

    // ---- CSR + graph segments + weight conversion (reused across layers)
    hist_kernel<<<eblk, 256, 0, stream>>>(ei, cnt, N_EDGES);
    scan_p1<<<NB_SCAN, 256, 0, stream>>>(cnt, bsum, N_NODES);
    scan_p2<<<1, 256, 0, stream>>>(bsum, bsoff, off, N_NODES);
    scan_p3<<<NB_SCAN, 256, 0, stream>>>(cnt, bsoff, off, N_NODES);
    scatter_kernel<<<eblk, 256, 0, stream>>>(ei, cnt, csr, N_EDGES);
    gstart_kernel<<<nblk, 256, 0, stream>>>(batch, gst, N_NODES);
    WPtrs wp;
    for (int l = 0; l < 3; ++l) {
        wp.w[l * 4 + 0] = Wk[l];
        wp.w[l * 4 + 1] = Wq[l];
        wp.w[l * 4 + 2] = Wv[l];
        wp.w[l * 4 + 3] = Wsk[l];
    }
    conv_W3<<<768, 256, 0, stream>>>(wp, Wt16);

    // ---- Layer 1
    conv_A<<<cablk, 256, 0, stream>>>(x, N_NODES, DIN, A16);
    gemm_mfma<<<ggrid, 256, 0, stream>>>(A16, Wt16,
        bk[0], bq[0], bv[0], bs[0], EKb, EQ16, V16, hbuf, N_NODES);
    agg_csr<1><<<ablk, 256, 0, stream>>>(EKb, EQ16, V16, off, csr, hbuf, A16, N_NODES);

    // ---- Layer 2
    gemm_mfma<<<ggrid, 256, 0, stream>>>(A16, Wt16 + 512 * 128,
        bk[1], bq[1], bv[1], bs[1], EKb, EQ16, V16, hbuf, N_NODES);
    agg_csr<1><<<ablk, 256, 0, stream>>>(EKb, EQ16, V16, off, csr, hbuf, A16, N_NODES);

    // ---- Layer 3
    gemm_mfma<<<ggrid, 256, 0, stream>>>(A16, Wt16 + 1024 * 128,
        bk[2], bq[2], bv[2], bs[2], EKb, EQ16, V16, hbuf, N_NODES);
    agg_csr<0><<<ablk, 256, 0, stream>>>(EKb, EQ16, V16, off, csr, hbuf, A16, N_NODES);

    // ---- Pool + MLP
    pool_seg<<<pgrid, 128, 0, stream>>>(hbuf, gst, hg);
    mlp_kernel<<<N_GRAPHS, 64, 0, stream>>>(hg, W4, b4, W5, b5, out);
}

// Round 14
// 399.889 us; speedup vs baseline: 1.3023x; 1.1697x over previous
//
#include <hip/hip_runtime.h>

#define N_NODES 50000
#define N_EDGES 800000
#define N_GRAPHS 256
#define DIN 126
#define H 128
#define MP 50048           // N_NODES padded to 128
#define NB_SCAN 196        // ceil(N_NODES/256)

typedef __attribute__((ext_vector_type(8))) _Float16 half8v;
typedef __attribute__((ext_vector_type(4))) _Float16 half4v;
typedef __attribute__((ext_vector_type(4))) float f32x4;
typedef __attribute__((ext_vector_type(2))) float f32x2;

// ---------------------------------------------------------------------------
// A conversion (layer-1 input only): X fp32 [M,Kd] -> A16 fp16 [MP][128]
// ---------------------------------------------------------------------------
__global__ __launch_bounds__(256) void conv_A(const float* __restrict__ X, int M, int Kd,
                                              _Float16* __restrict__ A16)
{
    const int t = blockIdx.x * 256 + threadIdx.x;
    const int row = t >> 4;
    if (row >= MP) return;
    const int k0 = (t & 15) * 8;
    half8v v8;
    #pragma unroll
    for (int j = 0; j < 8; ++j) {
        const int k = k0 + j;
        float v = 0.f;
        if (row < M && k < Kd) v = X[(size_t)row * Kd + k];
        v8[j] = (_Float16)v;
    }
    *(half8v*)&A16[(size_t)row * 128 + k0] = v8;
}

// ---------------------------------------------------------------------------
// W conversion, all 3 layers in one launch.
// ---------------------------------------------------------------------------
struct WPtrs { const float* w[12]; };

__global__ __launch_bounds__(256) void conv_W3(WPtrs P, _Float16* __restrict__ Wt16)
{
    const int t = blockIdx.x * 256 + threadIdx.x;
    if (t >= 3 * 512 * 128) return;
    const int layer = t >> 16;
    const int r = t & 65535;
    const int n = r >> 7, k = r & 127;
    const int mtx = n >> 7, cc = n & 127;
    const int Kd = (layer == 0) ? DIN : H;
    const float* W = P.w[layer * 4 + mtx];
    const float v = (k < Kd) ? W[(size_t)k * 128 + cc] : 0.f;
    Wt16[t] = (_Float16)v;
}

// ---------------------------------------------------------------------------
// MFMA GEMM v9 (R13 structure: swapped-operand D^T, vector row stores).
// Outputs: EK=exp(-K) fp32, EQ8=fp8(exp(-Q)), V8=fp8(V), S fp32.
// fp8 = OCP e4m3 via v_cvt_pk_fp8_f32 (saturates at 448, matching the
// true-gate limit for very negative Q).
// ---------------------------------------------------------------------------
__global__ __launch_bounds__(256, 5) void gemm_mfma(
    const _Float16* __restrict__ A16, const _Float16* __restrict__ Wt16,
    const float* __restrict__ bias0, const float* __restrict__ bias1,
    const float* __restrict__ bias2, const float* __restrict__ bias3,
    float* __restrict__ OEK, unsigned char* __restrict__ OEQ8,
    unsigned char* __restrict__ OV8, float* __restrict__ OS, int M)
{
    __shared__ _Float16 ldsA[2][64 * 64];  // [k-half][row*64 + slot*8], 16KB
    const int t = threadIdx.x;
    const int l = t & 63, wc = t >> 6;
    const int row0 = blockIdx.x * 64;
    const int mp = blockIdx.y;             // matrix pair: {0,1} or {2,3}
    const int fr = l & 15;
    const int kq = l >> 4;

    // ---- stage A: 1024 granules of 16B, 4 per thread
    #pragma unroll
    for (int i = 0; i < 4; ++i) {
        const int gi = i * 256 + t;        // 0..1023
        const int kh = gi >> 9;
        const int r = (gi >> 3) & 63;
        const int j = gi & 7;
        const int slot = j ^ (r & 7);
        *(half8v*)&ldsA[kh][r * 64 + slot * 8] =
            *(const half8v*)&A16[(size_t)(row0 + r) * 128 + kh * 64 + j * 8];
    }
    __syncthreads();   // the only barrier

    #pragma unroll
    for (int mi = 0; mi < 2; ++mi) {
        const int mtx = mp * 2 + mi;
        f32x4 acc[4][2] = {};
        #pragma unroll
        for (int step = 0; step < 4; ++step) {
            const int kg = step * 4 + kq;
            const int kh = kg >> 3, kk = kg & 7;
            half8v a[4];
            #pragma unroll
            for (int m = 0; m < 4; ++m) {
                const int ar = m * 16 + fr;
                const int slot = kk ^ (ar & 7);
                a[m] = *(const half8v*)&ldsA[kh][ar * 64 + slot * 8];
            }
            half8v w[2];
            #pragma unroll
            for (int n = 0; n < 2; ++n) {
                const size_t wo = (size_t)(mtx * 128 + wc * 32 + n * 16 + fr) * 128 + kg * 8;
                w[n] = *(const half8v*)&Wt16[wo];
            }
            // swapped operands: D^T -- lane = one node-row, 4 consecutive cols
            #pragma unroll
            for (int m = 0; m < 4; ++m)
                #pragma unroll
                for (int n = 0; n < 2; ++n)
                    acc[m][n] = __builtin_amdgcn_mfma_f32_16x16x32_f16(w[n], a[m], acc[m][n], 0, 0, 0);
        }
        // ---- epilogue: lane writes row r = row0+m*16+fr, cols c0..c0+3
        const float* bias = (mtx == 0) ? bias0 : (mtx == 1) ? bias1
                          : (mtx == 2) ? bias2 : bias3;
        if (mtx == 0) {
            #pragma unroll
            for (int n = 0; n < 2; ++n) {
                const int c0 = wc * 32 + n * 16 + kq * 4;
                const float4 bv = *(const float4*)&bias[c0];
                #pragma unroll
                for (int m = 0; m < 4; ++m) {
                    const int r = row0 + m * 16 + fr;
                    if (r < M) {
                        float4 o;
                        o.x = __expf(-(acc[m][n][0] + bv.x));
                        o.y = __expf(-(acc[m][n][1] + bv.y));
                        o.z = __expf(-(acc[m][n][2] + bv.z));
                        o.w = __expf(-(acc[m][n][3] + bv.w));
                        *(float4*)&OEK[(size_t)r * 128 + c0] = o;
                    }
                }
            }
        } else if (mtx == 1) {
            #pragma unroll
            for (int n = 0; n < 2; ++n) {
                const int c0 = wc * 32 + n * 16 + kq * 4;
                const float4 bv = *(const float4*)&bias[c0];
                #pragma unroll
                for (int m = 0; m < 4; ++m) {
                    const int r = row0 + m * 16 + fr;
                    if (r < M) {
                        const float e0 = __expf(-(acc[m][n][0] + bv.x));
                        const float e1 = __expf(-(acc[m][n][1] + bv.y));
                        const float e2 = __expf(-(acc[m][n][2] + bv.z));
                        const float e3 = __expf(-(acc[m][n][3] + bv.w));
                        int p = 0;
                        p = __builtin_amdgcn_cvt_pk_fp8_f32(e0, e1, p, false);
                        p = __builtin_amdgcn_cvt_pk_fp8_f32(e2, e3, p, true);
                        *(int*)&OEQ8[(size_t)r * 128 + c0] = p;
                    }
                }
            }
        } else if (mtx == 2) {
            #pragma unroll
            for (int n = 0; n < 2; ++n) {
                const int c0 = wc * 32 + n * 16 + kq * 4;
                const float4 bv = *(const float4*)&bias[c0];
                #pragma unroll
                for (int m = 0; m < 4; ++m) {
                    const int r = row0 + m * 16 + fr;
                    if (r < M) {
                        int p = 0;
                        p = __builtin_amdgcn_cvt_pk_fp8_f32(acc[m][n][0] + bv.x,
                                                            acc[m][n][1] + bv.y, p, false);
                        p = __builtin_amdgcn_cvt_pk_fp8_f32(acc[m][n][2] + bv.z,
                                                            acc[m][n][3] + bv.w, p, true);
                        *(int*)&OV8[(size_t)r * 128 + c0] = p;
                    }
                }
            }
        } else {
            #pragma unroll
            for (int n = 0; n < 2; ++n) {
                const int c0 = wc * 32 + n * 16 + kq * 4;
                const float4 bv = *(const float4*)&bias[c0];
                #pragma unroll
                for (int m = 0; m < 4; ++m) {
                    const int r = row0 + m * 16 + fr;
                    if (r < M) {
                        float4 o;
                        o.x = acc[m][n][0] + bv.x;
                        o.y = acc[m][n][1] + bv.y;
                        o.z = acc[m][n][2] + bv.z;
                        o.w = acc[m][n][3] + bv.w;
                        *(float4*)&OS[(size_t)r * 128 + c0] = o;
                    }
                }
            }
        }
    }
}

// ---------------------------------------------------------------------------
// CSR build (unchanged)
// ---------------------------------------------------------------------------
__global__ __launch_bounds__(256) void hist_kernel(const int* __restrict__ ei,
                                                   int* __restrict__ cnt, int E)
{
    const int e = blockIdx.x * 256 + threadIdx.x;
    if (e < E) atomicAdd(&cnt[ei[E + e]], 1);
}

__global__ __launch_bounds__(256) void scan_p1(const int* __restrict__ cnt,
                                               int* __restrict__ bsum, int Nn)
{
    __shared__ int red[256];
    const int t = threadIdx.x;
    const int i = blockIdx.x * 256 + t;
    red[t] = (i < Nn) ? cnt[i] : 0;
    __syncthreads();
    for (int d = 128; d > 0; d >>= 1) {
        if (t < d) red[t] += red[t + d];
        __syncthreads();
    }
    if (t == 0) bsum[blockIdx.x] = red[0];
}

__global__ __launch_bounds__(256) void scan_p2(const int* __restrict__ bsum,
                                               int* __restrict__ bsoff,
                                               int* __restrict__ off, int Nn)
{
    __shared__ int sc[256];
    const int t = threadIdx.x;
    const int v = (t < NB_SCAN) ? bsum[t] : 0;
    sc[t] = v;
    __syncthreads();
    #pragma unroll
    for (int d = 1; d < 256; d <<= 1) {
        const int a = (t >= d) ? sc[t - d] : 0;
        __syncthreads();
        sc[t] += a;
        __syncthreads();
    }
    if (t < NB_SCAN) bsoff[t] = sc[t] - v;
    if (t == NB_SCAN - 1) off[Nn] = sc[t];
}

__global__ __launch_bounds__(256) void scan_p3(int* __restrict__ cnt,
                                               const int* __restrict__ bsoff,
                                               int* __restrict__ off, int Nn)
{
    __shared__ int sc[256];
    const int t = threadIdx.x;
    const int i = blockIdx.x * 256 + t;
    const int v = (i < Nn) ? cnt[i] : 0;
    sc[t] = v;
    __syncthreads();
    #pragma unroll
    for (int d = 1; d < 256; d <<= 1) {
        const int a = (t >= d) ? sc[t - d] : 0;
        __syncthreads();
        sc[t] += a;
        __syncthreads();
    }
    if (i < Nn) {
        const int o = bsoff[blockIdx.x] + sc[t] - v;
        off[i] = o;
        cnt[i] = o;
    }
}

__global__ __launch_bounds__(256) void scatter_kernel(const int* __restrict__ ei,
                                                      int* __restrict__ cur,
                                                      int* __restrict__ csr_src, int E)
{
    const int e = blockIdx.x * 256 + threadIdx.x;
    if (e >= E) return;
    const int s = ei[e];
    const int d = ei[E + e];
    const int pos = atomicAdd(&cur[d], 1);
    csr_src[pos] = s;
}

// ---------------------------------------------------------------------------
// CSR aggregation v6: fp8 EQ/V gathers (8B/lane/edge), decode via
// v_cvt_pk_f32_fp8; gate = rcp(1 + ek*eq); 16 lanes/edge, unroll 4.
// ---------------------------------------------------------------------------
template<int FUSE>
__global__ __launch_bounds__(256) void agg_csr(
    const float* __restrict__ EKb, const unsigned char* __restrict__ EQ8,
    const unsigned char* __restrict__ V8, const int* __restrict__ off,
    const int* __restrict__ csr_src, float* __restrict__ hSkip,
    _Float16* __restrict__ A16, int Nn)
{
    const int node = blockIdx.x * 4 + (threadIdx.x >> 6);
    if (node >= Nn) return;
    const int lane = threadIdx.x & 63;
    const int grp = lane >> 4;
    const int sub = lane & 15;
    const int q = sub * 8;

    const float4 kA = *(const float4*)(EKb + (size_t)node * H + q);
    const float4 kB = *(const float4*)(EKb + (size_t)node * H + q + 4);
    float acc[8] = {};

    const int begin = off[node], end = off[node + 1];
    for (int j0 = begin; j0 < end; j0 += 64) {
        const int nrem = end - j0;
        const int nk = nrem < 64 ? nrem : 64;
        const int sv = (lane < nk) ? csr_src[j0 + lane] : 0;
        #pragma unroll 4
        for (int k = 0; k < nk; k += 4) {
            const int myk = k + grp;
            const int s = __shfl(sv, myk < nk ? myk : 0);
            if (myk < nk) {
                const uint2 q8 = *(const uint2*)(EQ8 + (size_t)s * H + q);
                const uint2 v8 = *(const uint2*)(V8 + (size_t)s * H + q);
                const f32x2 qa = __builtin_amdgcn_cvt_pk_f32_fp8(q8.x, false);
                const f32x2 qb = __builtin_amdgcn_cvt_pk_f32_fp8(q8.x, true);
                const f32x2 qc = __builtin_amdgcn_cvt_pk_f32_fp8(q8.y, false);
                const f32x2 qd = __builtin_amdgcn_cvt_pk_f32_fp8(q8.y, true);
                const f32x2 va = __builtin_amdgcn_cvt_pk_f32_fp8(v8.x, false);
                const f32x2 vb = __builtin_amdgcn_cvt_pk_f32_fp8(v8.x, true);
                const f32x2 vc = __builtin_amdgcn_cvt_pk_f32_fp8(v8.y, false);
                const f32x2 vd = __builtin_amdgcn_cvt_pk_f32_fp8(v8.y, true);
                acc[0] = fmaf(va[0], __builtin_amdgcn_rcpf(fmaf(kA.x, qa[0], 1.f)), acc[0]);
                acc[1] = fmaf(va[1], __builtin_amdgcn_rcpf(fmaf(kA.y, qa[1], 1.f)), acc[1]);
                acc[2] = fmaf(vb[0], __builtin_amdgcn_rcpf(fmaf(kA.z, qb[0], 1.f)), acc[2]);
                acc[3] = fmaf(vb[1], __builtin_amdgcn_rcpf(fmaf(kA.w, qb[1], 1.f)), acc[3]);
                acc[4] = fmaf(vc[0], __builtin_amdgcn_rcpf(fmaf(kB.x, qc[0], 1.f)), acc[4]);
                acc[5] = fmaf(vc[1], __builtin_amdgcn_rcpf(fmaf(kB.y, qc[1], 1.f)), acc[5]);
                acc[6] = fmaf(vd[0], __builtin_amdgcn_rcpf(fmaf(kB.z, qd[0], 1.f)), acc[6]);
                acc[7] = fmaf(vd[1], __builtin_amdgcn_rcpf(fmaf(kB.w, qd[1], 1.f)), acc[7]);
            }
        }
    }
    #pragma unroll
    for (int i = 0; i < 8; ++i) {
        acc[i] += __shfl_xor(acc[i], 16);
        acc[i] += __shfl_xor(acc[i], 32);
    }
    if (grp == 0) {
        const float* sk = hSkip + (size_t)node * H + q;
        const float4 eA = *(const float4*)sk;
        const float4 eB = *(const float4*)(sk + 4);
        float h[8];
        h[0] = eA.x + acc[0]; h[1] = eA.y + acc[1];
        h[2] = eA.z + acc[2]; h[3] = eA.w + acc[3];
        h[4] = eB.x + acc[4]; h[5] = eB.y + acc[5];
        h[6] = eB.z + acc[6]; h[7] = eB.w + acc[7];
        if (FUSE) {
            half8v hv;
            #pragma unroll
            for (int j = 0; j < 8; ++j)
                hv[j] = (_Float16)fmaxf(h[j], 0.f);
            *(half8v*)&A16[(size_t)node * 128 + q] = hv;
        } else {
            float* o = hSkip + (size_t)node * H + q;
            *(float4*)o = make_float4(h[0], h[1], h[2], h[3]);
            *(float4*)(o + 4) = make_float4(h[4], h[5], h[6], h[7]);
        }
    }
}

// ---------------------------------------------------------------------------
// Pool + MLP (unchanged)
// ---------------------------------------------------------------------------
__global__ __launch_bounds__(256) void gstart_kernel(const int* __restrict__ batch,
                                                     int* __restrict__ gstart, int Nn)
{
    const int n = blockIdx.x * 256 + threadIdx.x;
    if (n >= Nn) return;
    const int b = batch[n];
    const int bp = (n == 0) ? -1 : batch[n - 1];
    for (int g = bp + 1; g <= b; ++g) gstart[g] = n;
    if (n == Nn - 1)
        for (int g = b + 1; g <= N_GRAPHS; ++g) gstart[g] = Nn;
}

__global__ __launch_bounds__(128) void pool_seg(const float* __restrict__ h,
                                                const int* __restrict__ gstart,
                                                float* __restrict__ hg)
{
    const int g = blockIdx.x;
    const int part = blockIdx.y;
    const int t = threadIdx.x;
    const int b0 = gstart[g], b1 = gstart[g + 1];
    float acc = 0.f;
    for (int n = b0 + part; n < b1; n += 4) acc += h[(size_t)n * H + t];
    atomicAdd(&hg[(size_t)g * H + t], acc);
}

__global__ __launch_bounds__(64) void mlp_kernel(
    const float* __restrict__ hg,
    const float* __restrict__ W4, const float* __restrict__ b4,
    const float* __restrict__ W5, const float* __restrict__ b5,
    float* __restrict__ out)
{
    const int g = blockIdx.x;
    const int c = threadIdx.x;
    __shared__ float hrow[H];
    for (int k = c; k < H; k += 64) hrow[k] = hg[(size_t)g * H + k];
    __syncthreads();
    float s = b4[c];
    #pragma unroll 8
    for (int k = 0; k < H; ++k) s += hrow[k] * W4[(size_t)k * 64 + c];
    s = fmaxf(s, 0.f) * W5[c];
    #pragma unroll
    for (int off = 32; off > 0; off >>= 1) s += __shfl_down(s, off);
    if (c == 0) out[g] = 1.f / (1.f + __expf(-(s + b5[0])));
}

// ---------------------------------------------------------------------------
extern "C" void kernel_launch(void* const* d_in, const int* in_sizes, int n_in,
                              void* d_out, int out_size, void* d_ws, size_t ws_size,
                              hipStream_t stream)
{
    const float* x = (const float*)d_in[0];
    const float *Wk[3], *bk[3], *Wq[3], *bq[3], *Wv[3], *bv[3], *Wsk[3], *bs[3];
    for (int l = 0; l < 3; ++l) {
        const int base = 2 + l * 8;
        Wk[l]  = (const float*)d_in[base + 0]; bk[l] = (const float*)d_in[base + 1];
        Wq[l]  = (const float*)d_in[base + 2]; bq[l] = (const float*)d_in[base + 3];
        Wv[l]  = (const float*)d_in[base + 4]; bv[l] = (const float*)d_in[base + 5];
        Wsk[l] = (const float*)d_in[base + 6]; bs[l] = (const float*)d_in[base + 7];
    }
    const float* W4 = (const float*)d_in[26];
    const float* b4 = (const float*)d_in[27];
    const float* W5 = (const float*)d_in[28];
    const float* b5 = (const float*)d_in[29];
    const int* ei    = (const int*)d_in[30];
    const int* batch = (const int*)d_in[31];
    float* out = (float*)d_out;

    const size_t NH = (size_t)N_NODES * H;
    const size_t AH = (size_t)MP * 128;
    const size_t WH3 = (size_t)3 * 512 * 128;
    float*         EKb  = (float*)d_ws;
    float*         hbuf = EKb + NH;
    unsigned char* EQ8  = (unsigned char*)(hbuf + NH);
    unsigned char* V8   = EQ8 + NH;
    _Float16*      A16  = (_Float16*)(V8 + NH);
    _Float16*      Wt16 = A16 + AH;
    float*         hg   = (float*)(Wt16 + WH3);               // G*H (zeroed)
    int*           off  = (int*)(hg + (size_t)N_GRAPHS * H);  // N+1 (zeroed)
    int*           cnt  = off + (N_NODES + 1);                // N   (zeroed)
    int*           csr  = cnt + N_NODES;                      // E
    int*           gst  = csr + N_EDGES;                      // G+1
    int*           bsum = gst + (N_GRAPHS + 1);               // 256
    int*           bsoff= bsum + 256;                         // 256
    const size_t need = (2 * NH + (size_t)N_GRAPHS * H) * sizeof(float)
                      + 2 * NH * sizeof(unsigned char)
                      + (AH + WH3) * sizeof(_Float16)
                      + (size_t)(2 * N_NODES + 1 + N_EDGES + N_GRAPHS + 1 + 512) * sizeof(int);
    if (ws_size < need) return;

    const int eblk = (N_EDGES + 255) / 256;
    const int ablk = (N_NODES + 3) / 4;
    const int nblk = (N_NODES + 255) / 256;
    const int cablk = (MP * 16) / 256;
    const dim3 ggrid(MP / 64, 2);        // 782 x 2 = 1564 blocks
    const dim3 pgrid(N_GRAPHS, 4);

    // ---- one fused memset: hg (pool accum) + off + cnt (contiguous)
    hipMemsetAsync(hg, 0,
        ((size_t)N_GRAPHS * H + 2 * N_NODES + 1) * sizeof(int), stream);

    // ---- CSR + graph segments + weight conversion (reused across layers)
    hist_kernel<<<eblk, 256, 0, stream>>>(ei, cnt, N_EDGES);
    scan_p1<<<NB_SCAN, 256, 0, stream>>>(cnt, bsum, N_NODES);
    scan_p2<<<1, 256, 0, stream>>>(bsum, bsoff, off, N_NODES);
    scan_p3<<<NB_SCAN, 256, 0, stream>>>(cnt, bsoff, off, N_NODES);
    scatter_kernel<<<eblk, 256, 0, stream>>>(ei, cnt, csr, N_EDGES);
    gstart_kernel<<<nblk, 256, 0, stream>>>(batch, gst, N_NODES);
    WPtrs wp;
    for (int l = 0; l < 3; ++l) {
        wp.w[l * 4 + 0] = Wk[l];
        wp.w[l * 4 + 1] = Wq[l];
        wp.w[l * 4 + 2] = Wv[l];
        wp.w[l * 4 + 3] = Wsk[l];
    }
    conv_W3<<<768, 256, 0, stream>>>(wp, Wt16);

    // ---- Layer 1
    conv_A<<<cablk, 256, 0, stream>>>(x, N_NODES, DIN, A16);
    gemm_mfma<<<ggrid, 256, 0, stream>>>(A16, Wt16,
        bk[0], bq[0], bv[0], bs[0], EKb, EQ8, V8, hbuf, N_NODES);
    agg_csr<1><<<ablk, 256, 0, stream>>>(EKb, EQ8, V8, off, csr, hbuf, A16, N_NODES);

    // ---- Layer 2
    gemm_mfma<<<ggrid, 256, 0, stream>>>(A16, Wt16 + 512 * 128,
        bk[1], bq[1], bv[1], bs[1], EKb, EQ8, V8, hbuf, N_NODES);
    agg_csr<1><<<ablk, 256, 0, stream>>>(EKb, EQ8, V8, off, csr, hbuf, A16, N_NODES);

    // ---- Layer 3
    gemm_mfma<<<ggrid, 256, 0, stream>>>(A16, Wt16 + 1024 * 128,
        bk[2], bq[2], bv[2], bs[2], EKb, EQ8, V8, hbuf, N_NODES);
    agg_csr<0><<<ablk, 256, 0, stream>>>(EKb, EQ8, V8, off, csr, hbuf, A16, N_NODES);

    // ---- Pool + MLP
    pool_seg<<<pgrid, 128, 0, stream>>>(hbuf, gst, hg);
    mlp_kernel<<<N_GRAPHS, 64, 0, stream>>>(hg, W4, b4, W5, b5, out);
}

// Round 15
// 388.199 us; speedup vs baseline: 1.3415x; 1.0301x over previous
//
#include <hip/hip_runtime.h>

#define N_NODES 50000
#define N_EDGES 800000
#define N_GRAPHS 256
#define DIN 126
#define H 128
#define MP 50048           // N_NODES padded to 128
#define NB_SCAN 196        // ceil(N_NODES/256)

typedef __attribute__((ext_vector_type(8))) _Float16 half8v;
typedef __attribute__((ext_vector_type(4))) _Float16 half4v;
typedef __attribute__((ext_vector_type(4))) float f32x4;
typedef __attribute__((ext_vector_type(2))) float f32x2;

// ---------------------------------------------------------------------------
// A conversion (layer-1 input only): X fp32 [M,Kd] -> A16 fp16 [MP][128]
// ---------------------------------------------------------------------------
__global__ __launch_bounds__(256) void conv_A(const float* __restrict__ X, int M, int Kd,
                                              _Float16* __restrict__ A16)
{
    const int t = blockIdx.x * 256 + threadIdx.x;
    const int row = t >> 4;
    if (row >= MP) return;
    const int k0 = (t & 15) * 8;
    half8v v8;
    #pragma unroll
    for (int j = 0; j < 8; ++j) {
        const int k = k0 + j;
        float v = 0.f;
        if (row < M && k < Kd) v = X[(size_t)row * Kd + k];
        v8[j] = (_Float16)v;
    }
    *(half8v*)&A16[(size_t)row * 128 + k0] = v8;
}

// ---------------------------------------------------------------------------
// W conversion, all 3 layers in one launch.
// ---------------------------------------------------------------------------
struct WPtrs { const float* w[12]; };

__global__ __launch_bounds__(256) void conv_W3(WPtrs P, _Float16* __restrict__ Wt16)
{
    const int t = blockIdx.x * 256 + threadIdx.x;
    if (t >= 3 * 512 * 128) return;
    const int layer = t >> 16;
    const int r = t & 65535;
    const int n = r >> 7, k = r & 127;
    const int mtx = n >> 7, cc = n & 127;
    const int Kd = (layer == 0) ? DIN : H;
    const float* W = P.w[layer * 4 + mtx];
    const float v = (k < Kd) ? W[(size_t)k * 128 + cc] : 0.f;
    Wt16[t] = (_Float16)v;
}

// ---------------------------------------------------------------------------
// MFMA GEMM v10 (R13 structure: swapped-operand D^T, vector row stores).
// All outputs narrow: EK=fp16(exp(-K)), EQ8=fp8(exp(-Q)), V8=fp8(V),
// S=fp16 (h skip).  Logical writes 64MB -> 38.4MB per dispatch.
// ---------------------------------------------------------------------------
__global__ __launch_bounds__(256, 5) void gemm_mfma(
    const _Float16* __restrict__ A16, const _Float16* __restrict__ Wt16,
    const float* __restrict__ bias0, const float* __restrict__ bias1,
    const float* __restrict__ bias2, const float* __restrict__ bias3,
    _Float16* __restrict__ OEK, unsigned char* __restrict__ OEQ8,
    unsigned char* __restrict__ OV8, _Float16* __restrict__ OS, int M)
{
    __shared__ _Float16 ldsA[2][64 * 64];  // [k-half][row*64 + slot*8], 16KB
    const int t = threadIdx.x;
    const int l = t & 63, wc = t >> 6;
    const int row0 = blockIdx.x * 64;
    const int mp = blockIdx.y;             // matrix pair: {0,1} or {2,3}
    const int fr = l & 15;
    const int kq = l >> 4;

    // ---- stage A: 1024 granules of 16B, 4 per thread
    #pragma unroll
    for (int i = 0; i < 4; ++i) {
        const int gi = i * 256 + t;        // 0..1023
        const int kh = gi >> 9;
        const int r = (gi >> 3) & 63;
        const int j = gi & 7;
        const int slot = j ^ (r & 7);
        *(half8v*)&ldsA[kh][r * 64 + slot * 8] =
            *(const half8v*)&A16[(size_t)(row0 + r) * 128 + kh * 64 + j * 8];
    }
    __syncthreads();   // the only barrier

    #pragma unroll
    for (int mi = 0; mi < 2; ++mi) {
        const int mtx = mp * 2 + mi;
        f32x4 acc[4][2] = {};
        #pragma unroll
        for (int step = 0; step < 4; ++step) {
            const int kg = step * 4 + kq;
            const int kh = kg >> 3, kk = kg & 7;
            half8v a[4];
            #pragma unroll
            for (int m = 0; m < 4; ++m) {
                const int ar = m * 16 + fr;
                const int slot = kk ^ (ar & 7);
                a[m] = *(const half8v*)&ldsA[kh][ar * 64 + slot * 8];
            }
            half8v w[2];
            #pragma unroll
            for (int n = 0; n < 2; ++n) {
                const size_t wo = (size_t)(mtx * 128 + wc * 32 + n * 16 + fr) * 128 + kg * 8;
                w[n] = *(const half8v*)&Wt16[wo];
            }
            // swapped operands: D^T -- lane = one node-row, 4 consecutive cols
            #pragma unroll
            for (int m = 0; m < 4; ++m)
                #pragma unroll
                for (int n = 0; n < 2; ++n)
                    acc[m][n] = __builtin_amdgcn_mfma_f32_16x16x32_f16(w[n], a[m], acc[m][n], 0, 0, 0);
        }
        // ---- epilogue: lane writes row r = row0+m*16+fr, cols c0..c0+3
        const float* bias = (mtx == 0) ? bias0 : (mtx == 1) ? bias1
                          : (mtx == 2) ? bias2 : bias3;
        if (mtx == 0) {
            #pragma unroll
            for (int n = 0; n < 2; ++n) {
                const int c0 = wc * 32 + n * 16 + kq * 4;
                const float4 bv = *(const float4*)&bias[c0];
                #pragma unroll
                for (int m = 0; m < 4; ++m) {
                    const int r = row0 + m * 16 + fr;
                    if (r < M) {
                        half4v o;
                        o[0] = (_Float16)__expf(-(acc[m][n][0] + bv.x));
                        o[1] = (_Float16)__expf(-(acc[m][n][1] + bv.y));
                        o[2] = (_Float16)__expf(-(acc[m][n][2] + bv.z));
                        o[3] = (_Float16)__expf(-(acc[m][n][3] + bv.w));
                        *(half4v*)&OEK[(size_t)r * 128 + c0] = o;
                    }
                }
            }
        } else if (mtx == 1) {
            #pragma unroll
            for (int n = 0; n < 2; ++n) {
                const int c0 = wc * 32 + n * 16 + kq * 4;
                const float4 bv = *(const float4*)&bias[c0];
                #pragma unroll
                for (int m = 0; m < 4; ++m) {
                    const int r = row0 + m * 16 + fr;
                    if (r < M) {
                        const float e0 = __expf(-(acc[m][n][0] + bv.x));
                        const float e1 = __expf(-(acc[m][n][1] + bv.y));
                        const float e2 = __expf(-(acc[m][n][2] + bv.z));
                        const float e3 = __expf(-(acc[m][n][3] + bv.w));
                        int p = 0;
                        p = __builtin_amdgcn_cvt_pk_fp8_f32(e0, e1, p, false);
                        p = __builtin_amdgcn_cvt_pk_fp8_f32(e2, e3, p, true);
                        *(int*)&OEQ8[(size_t)r * 128 + c0] = p;
                    }
                }
            }
        } else if (mtx == 2) {
            #pragma unroll
            for (int n = 0; n < 2; ++n) {
                const int c0 = wc * 32 + n * 16 + kq * 4;
                const float4 bv = *(const float4*)&bias[c0];
                #pragma unroll
                for (int m = 0; m < 4; ++m) {
                    const int r = row0 + m * 16 + fr;
                    if (r < M) {
                        int p = 0;
                        p = __builtin_amdgcn_cvt_pk_fp8_f32(acc[m][n][0] + bv.x,
                                                            acc[m][n][1] + bv.y, p, false);
                        p = __builtin_amdgcn_cvt_pk_fp8_f32(acc[m][n][2] + bv.z,
                                                            acc[m][n][3] + bv.w, p, true);
                        *(int*)&OV8[(size_t)r * 128 + c0] = p;
                    }
                }
            }
        } else {
            #pragma unroll
            for (int n = 0; n < 2; ++n) {
                const int c0 = wc * 32 + n * 16 + kq * 4;
                const float4 bv = *(const float4*)&bias[c0];
                #pragma unroll
                for (int m = 0; m < 4; ++m) {
                    const int r = row0 + m * 16 + fr;
                    if (r < M) {
                        half4v o;
                        o[0] = (_Float16)(acc[m][n][0] + bv.x);
                        o[1] = (_Float16)(acc[m][n][1] + bv.y);
                        o[2] = (_Float16)(acc[m][n][2] + bv.z);
                        o[3] = (_Float16)(acc[m][n][3] + bv.w);
                        *(half4v*)&OS[(size_t)r * 128 + c0] = o;
                    }
                }
            }
        }
    }
}

// ---------------------------------------------------------------------------
// CSR build (unchanged)
// ---------------------------------------------------------------------------
__global__ __launch_bounds__(256) void hist_kernel(const int* __restrict__ ei,
                                                   int* __restrict__ cnt, int E)
{
    const int e = blockIdx.x * 256 + threadIdx.x;
    if (e < E) atomicAdd(&cnt[ei[E + e]], 1);
}

__global__ __launch_bounds__(256) void scan_p1(const int* __restrict__ cnt,
                                               int* __restrict__ bsum, int Nn)
{
    __shared__ int red[256];
    const int t = threadIdx.x;
    const int i = blockIdx.x * 256 + t;
    red[t] = (i < Nn) ? cnt[i] : 0;
    __syncthreads();
    for (int d = 128; d > 0; d >>= 1) {
        if (t < d) red[t] += red[t + d];
        __syncthreads();
    }
    if (t == 0) bsum[blockIdx.x] = red[0];
}

__global__ __launch_bounds__(256) void scan_p2(const int* __restrict__ bsum,
                                               int* __restrict__ bsoff,
                                               int* __restrict__ off, int Nn)
{
    __shared__ int sc[256];
    const int t = threadIdx.x;
    const int v = (t < NB_SCAN) ? bsum[t] : 0;
    sc[t] = v;
    __syncthreads();
    #pragma unroll
    for (int d = 1; d < 256; d <<= 1) {
        const int a = (t >= d) ? sc[t - d] : 0;
        __syncthreads();
        sc[t] += a;
        __syncthreads();
    }
    if (t < NB_SCAN) bsoff[t] = sc[t] - v;
    if (t == NB_SCAN - 1) off[Nn] = sc[t];
}

__global__ __launch_bounds__(256) void scan_p3(int* __restrict__ cnt,
                                               const int* __restrict__ bsoff,
                                               int* __restrict__ off, int Nn)
{
    __shared__ int sc[256];
    const int t = threadIdx.x;
    const int i = blockIdx.x * 256 + t;
    const int v = (i < Nn) ? cnt[i] : 0;
    sc[t] = v;
    __syncthreads();
    #pragma unroll
    for (int d = 1; d < 256; d <<= 1) {
        const int a = (t >= d) ? sc[t - d] : 0;
        __syncthreads();
        sc[t] += a;
        __syncthreads();
    }
    if (i < Nn) {
        const int o = bsoff[blockIdx.x] + sc[t] - v;
        off[i] = o;
        cnt[i] = o;
    }
}

__global__ __launch_bounds__(256) void scatter_kernel(const int* __restrict__ ei,
                                                      int* __restrict__ cur,
                                                      int* __restrict__ csr_src, int E)
{
    const int e = blockIdx.x * 256 + threadIdx.x;
    if (e >= E) return;
    const int s = ei[e];
    const int d = ei[E + e];
    const int pos = atomicAdd(&cur[d], 1);
    csr_src[pos] = s;
}

// ---------------------------------------------------------------------------
// CSR aggregation v7: fp8 EQ/V gathers, fp16 EK and skip; gate = rcp(1+ek*eq).
// FUSE=1: writes next layer's fp16 A (relu fused).  FUSE=0: writes fp16 h.
// ---------------------------------------------------------------------------
template<int FUSE>
__global__ __launch_bounds__(256) void agg_csr(
    const _Float16* __restrict__ EKb, const unsigned char* __restrict__ EQ8,
    const unsigned char* __restrict__ V8, const int* __restrict__ off,
    const int* __restrict__ csr_src, _Float16* __restrict__ hSkip,
    _Float16* __restrict__ A16, int Nn)
{
    const int node = blockIdx.x * 4 + (threadIdx.x >> 6);
    if (node >= Nn) return;
    const int lane = threadIdx.x & 63;
    const int grp = lane >> 4;
    const int sub = lane & 15;
    const int q = sub * 8;

    const half8v ek8 = *(const half8v*)(EKb + (size_t)node * H + q);
    float ek[8];
    #pragma unroll
    for (int i = 0; i < 8; ++i) ek[i] = (float)ek8[i];
    float acc[8] = {};

    const int begin = off[node], end = off[node + 1];
    for (int j0 = begin; j0 < end; j0 += 64) {
        const int nrem = end - j0;
        const int nk = nrem < 64 ? nrem : 64;
        const int sv = (lane < nk) ? csr_src[j0 + lane] : 0;
        #pragma unroll 4
        for (int k = 0; k < nk; k += 4) {
            const int myk = k + grp;
            const int s = __shfl(sv, myk < nk ? myk : 0);
            if (myk < nk) {
                const uint2 q8 = *(const uint2*)(EQ8 + (size_t)s * H + q);
                const uint2 v8 = *(const uint2*)(V8 + (size_t)s * H + q);
                const f32x2 qa = __builtin_amdgcn_cvt_pk_f32_fp8(q8.x, false);
                const f32x2 qb = __builtin_amdgcn_cvt_pk_f32_fp8(q8.x, true);
                const f32x2 qc = __builtin_amdgcn_cvt_pk_f32_fp8(q8.y, false);
                const f32x2 qd = __builtin_amdgcn_cvt_pk_f32_fp8(q8.y, true);
                const f32x2 va = __builtin_amdgcn_cvt_pk_f32_fp8(v8.x, false);
                const f32x2 vb = __builtin_amdgcn_cvt_pk_f32_fp8(v8.x, true);
                const f32x2 vc = __builtin_amdgcn_cvt_pk_f32_fp8(v8.y, false);
                const f32x2 vd = __builtin_amdgcn_cvt_pk_f32_fp8(v8.y, true);
                acc[0] = fmaf(va[0], __builtin_amdgcn_rcpf(fmaf(ek[0], qa[0], 1.f)), acc[0]);
                acc[1] = fmaf(va[1], __builtin_amdgcn_rcpf(fmaf(ek[1], qa[1], 1.f)), acc[1]);
                acc[2] = fmaf(vb[0], __builtin_amdgcn_rcpf(fmaf(ek[2], qb[0], 1.f)), acc[2]);
                acc[3] = fmaf(vb[1], __builtin_amdgcn_rcpf(fmaf(ek[3], qb[1], 1.f)), acc[3]);
                acc[4] = fmaf(vc[0], __builtin_amdgcn_rcpf(fmaf(ek[4], qc[0], 1.f)), acc[4]);
                acc[5] = fmaf(vc[1], __builtin_amdgcn_rcpf(fmaf(ek[5], qc[1], 1.f)), acc[5]);
                acc[6] = fmaf(vd[0], __builtin_amdgcn_rcpf(fmaf(ek[6], qd[0], 1.f)), acc[6]);
                acc[7] = fmaf(vd[1], __builtin_amdgcn_rcpf(fmaf(ek[7], qd[1], 1.f)), acc[7]);
            }
        }
    }
    #pragma unroll
    for (int i = 0; i < 8; ++i) {
        acc[i] += __shfl_xor(acc[i], 16);
        acc[i] += __shfl_xor(acc[i], 32);
    }
    if (grp == 0) {
        const half8v sk8 = *(const half8v*)(hSkip + (size_t)node * H + q);
        half8v hv;
        if (FUSE) {
            #pragma unroll
            for (int j = 0; j < 8; ++j)
                hv[j] = (_Float16)fmaxf((float)sk8[j] + acc[j], 0.f);
            *(half8v*)&A16[(size_t)node * 128 + q] = hv;
        } else {
            #pragma unroll
            for (int j = 0; j < 8; ++j)
                hv[j] = (_Float16)((float)sk8[j] + acc[j]);
            *(half8v*)&hSkip[(size_t)node * H + q] = hv;
        }
    }
}

// ---------------------------------------------------------------------------
// Pool (fp16 h) + MLP
// ---------------------------------------------------------------------------
__global__ __launch_bounds__(256) void gstart_kernel(const int* __restrict__ batch,
                                                     int* __restrict__ gstart, int Nn)
{
    const int n = blockIdx.x * 256 + threadIdx.x;
    if (n >= Nn) return;
    const int b = batch[n];
    const int bp = (n == 0) ? -1 : batch[n - 1];
    for (int g = bp + 1; g <= b; ++g) gstart[g] = n;
    if (n == Nn - 1)
        for (int g = b + 1; g <= N_GRAPHS; ++g) gstart[g] = Nn;
}

__global__ __launch_bounds__(128) void pool_seg(const _Float16* __restrict__ h,
                                                const int* __restrict__ gstart,
                                                float* __restrict__ hg)
{
    const int g = blockIdx.x;
    const int part = blockIdx.y;
    const int t = threadIdx.x;
    const int b0 = gstart[g], b1 = gstart[g + 1];
    float acc = 0.f;
    for (int n = b0 + part; n < b1; n += 4) acc += (float)h[(size_t)n * H + t];
    atomicAdd(&hg[(size_t)g * H + t], acc);
}

__global__ __launch_bounds__(64) void mlp_kernel(
    const float* __restrict__ hg,
    const float* __restrict__ W4, const float* __restrict__ b4,
    const float* __restrict__ W5, const float* __restrict__ b5,
    float* __restrict__ out)
{
    const int g = blockIdx.x;
    const int c = threadIdx.x;
    __shared__ float hrow[H];
    for (int k = c; k < H; k += 64) hrow[k] = hg[(size_t)g * H + k];
    __syncthreads();
    float s = b4[c];
    #pragma unroll 8
    for (int k = 0; k < H; ++k) s += hrow[k] * W4[(size_t)k * 64 + c];
    s = fmaxf(s, 0.f) * W5[c];
    #pragma unroll
    for (int off = 32; off > 0; off >>= 1) s += __shfl_down(s, off);
    if (c == 0) out[g] = 1.f / (1.f + __expf(-(s + b5[0])));
}

// ---------------------------------------------------------------------------
extern "C" void kernel_launch(void* const* d_in, const int* in_sizes, int n_in,
                              void* d_out, int out_size, void* d_ws, size_t ws_size,
                              hipStream_t stream)
{
    const float* x = (const float*)d_in[0];
    const float *Wk[3], *bk[3], *Wq[3], *bq[3], *Wv[3], *bv[3], *Wsk[3], *bs[3];
    for (int l = 0; l < 3; ++l) {
        const int base = 2 + l * 8;
        Wk[l]  = (const float*)d_in[base + 0]; bk[l] = (const float*)d_in[base + 1];
        Wq[l]  = (const float*)d_in[base + 2]; bq[l] = (const float*)d_in[base + 3];
        Wv[l]  = (const float*)d_in[base + 4]; bv[l] = (const float*)d_in[base + 5];
        Wsk[l] = (const float*)d_in[base + 6]; bs[l] = (const float*)d_in[base + 7];
    }
    const float* W4 = (const float*)d_in[26];
    const float* b4 = (const float*)d_in[27];
    const float* W5 = (const float*)d_in[28];
    const float* b5 = (const float*)d_in[29];
    const int* ei    = (const int*)d_in[30];
    const int* batch = (const int*)d_in[31];
    float* out = (float*)d_out;

    const size_t NH = (size_t)N_NODES * H;
    const size_t AH = (size_t)MP * 128;
    const size_t WH3 = (size_t)3 * 512 * 128;
    _Float16*      EKb  = (_Float16*)d_ws;                    // NH halfs
    _Float16*      hbuf = EKb + NH;                           // NH halfs
    unsigned char* EQ8  = (unsigned char*)(hbuf + NH);        // NH bytes
    unsigned char* V8   = EQ8 + NH;                           // NH bytes
    _Float16*      A16  = (_Float16*)(V8 + NH);               // AH halfs
    _Float16*      Wt16 = A16 + AH;                           // WH3 halfs
    float*         hg   = (float*)(Wt16 + WH3);               // G*H (zeroed)
    int*           off  = (int*)(hg + (size_t)N_GRAPHS * H);  // N+1 (zeroed)
    int*           cnt  = off + (N_NODES + 1);                // N   (zeroed)
    int*           csr  = cnt + N_NODES;                      // E
    int*           gst  = csr + N_EDGES;                      // G+1
    int*           bsum = gst + (N_GRAPHS + 1);               // 256
    int*           bsoff= bsum + 256;                         // 256
    const size_t need = (size_t)N_GRAPHS * H * sizeof(float)
                      + 2 * NH * sizeof(unsigned char)
                      + (2 * NH + AH + WH3) * sizeof(_Float16)
                      + (size_t)(2 * N_NODES + 1 + N_EDGES + N_GRAPHS + 1 + 512) * sizeof(int);
    if (ws_size < need) return;

    const int eblk = (N_EDGES + 255) / 256;
    const int ablk = (N_NODES + 3) / 4;
    const int nblk = (N_NODES + 255) / 256;
    const int cablk = (MP * 16) / 256;
    const dim3 ggrid(MP / 64, 2);        // 782 x 2 = 1564 blocks
    const dim3 pgrid(N_GRAPHS, 4);

    // ---- one fused memset: hg (pool accum) + off + cnt (contiguous)
    hipMemsetAsync(hg, 0,
        ((size_t)N_GRAPHS * H + 2 * N_NODES + 1) * sizeof(int), stream);

    // ---- CSR + graph segments + weight conversion (reused across layers)
    hist_kernel<<<eblk, 256, 0, stream>>>(ei, cnt, N_EDGES);
    scan_p1<<<NB_SCAN, 256, 0, stream>>>(cnt, bsum, N_NODES);
    scan_p2<<<1, 256, 0, stream>>>(bsum, bsoff, off, N_NODES);
    scan_p3<<<NB_SCAN, 256, 0, stream>>>(cnt, bsoff, off, N_NODES);
    scatter_kernel<<<eblk, 256, 0, stream>>>(ei, cnt, csr, N_EDGES);
    gstart_kernel<<<nblk, 256, 0, stream>>>(batch, gst, N_NODES);
    WPtrs wp;
    for (int l = 0; l < 3; ++l) {
        wp.w[l * 4 + 0] = Wk[l];
        wp.w[l * 4 + 1] = Wq[l];
        wp.w[l * 4 + 2] = Wv[l];
        wp.w[l * 4 + 3] = Wsk[l];
    }
    conv_W3<<<768, 256, 0, stream>>>(wp, Wt16);

    // ---- Layer 1
    conv_A<<<cablk, 256, 0, stream>>>(x, N_NODES, DIN, A16);
    gemm_mfma<<<ggrid, 256, 0, stream>>>(A16, Wt16,
        bk[0], bq[0], bv[0], bs[0], EKb, EQ8, V8, hbuf, N_NODES);
    agg_csr<1><<<ablk, 256, 0, stream>>>(EKb, EQ8, V8, off, csr, hbuf, A16, N_NODES);

    // ---- Layer 2
    gemm_mfma<<<ggrid, 256, 0, stream>>>(A16, Wt16 + 512 * 128,
        bk[1], bq[1], bv[1], bs[1], EKb, EQ8, V8, hbuf, N_NODES);
    agg_csr<1><<<ablk, 256, 0, stream>>>(EKb, EQ8, V8, off, csr, hbuf, A16, N_NODES);

    // ---- Layer 3
    gemm_mfma<<<ggrid, 256, 0, stream>>>(A16, Wt16 + 1024 * 128,
        bk[2], bq[2], bv[2], bs[2], EKb, EQ8, V8, hbuf, N_NODES);
    agg_csr<0><<<ablk, 256, 0, stream>>>(EKb, EQ8, V8, off, csr, hbuf, A16, N_NODES);

    // ---- Pool + MLP
    pool_seg<<<pgrid, 128, 0, stream>>>(hbuf, gst, hg);
    mlp_kernel<<<N_GRAPHS, 64, 0, stream>>>(hg, W4, b4, W5, b5, out);
}

// Round 16
// 340.559 us; speedup vs baseline: 1.5291x; 1.1399x over previous
//
#include <hip/hip_runtime.h>

#define N_NODES 50000
#define N_EDGES 800000
#define N_GRAPHS 256
#define DIN 126
#define H 128
#define MP 50048           // N_NODES padded to 128
#define NBKT 196           // coarse buckets = dst>>8 (max 49999>>8 = 195)
#define NBA 100            // phase-A blocks
#define CHA 8000           // edges per phase-A block (100*8000 = 800000 exact)

typedef __attribute__((ext_vector_type(8))) _Float16 half8v;
typedef __attribute__((ext_vector_type(4))) _Float16 half4v;
typedef __attribute__((ext_vector_type(4))) float f32x4;
typedef __attribute__((ext_vector_type(2))) float f32x2;

// ---------------------------------------------------------------------------
// A conversion (layer-1 input only): X fp32 [M,Kd] -> A16 fp16 [MP][128]
// ---------------------------------------------------------------------------
__global__ __launch_bounds__(256) void conv_A(const float* __restrict__ X, int M, int Kd,
                                              _Float16* __restrict__ A16)
{
    const int t = blockIdx.x * 256 + threadIdx.x;
    const int row = t >> 4;
    if (row >= MP) return;
    const int k0 = (t & 15) * 8;
    half8v v8;
    #pragma unroll
    for (int j = 0; j < 8; ++j) {
        const int k = k0 + j;
        float v = 0.f;
        if (row < M && k < Kd) v = X[(size_t)row * Kd + k];
        v8[j] = (_Float16)v;
    }
    *(half8v*)&A16[(size_t)row * 128 + k0] = v8;
}

// ---------------------------------------------------------------------------
// W conversion, all 3 layers in one launch.
// ---------------------------------------------------------------------------
struct WPtrs { const float* w[12]; };

__global__ __launch_bounds__(256) void conv_W3(WPtrs P, _Float16* __restrict__ Wt16)
{
    const int t = blockIdx.x * 256 + threadIdx.x;
    if (t >= 3 * 512 * 128) return;
    const int layer = t >> 16;
    const int r = t & 65535;
    const int n = r >> 7, k = r & 127;
    const int mtx = n >> 7, cc = n & 127;
    const int Kd = (layer == 0) ? DIN : H;
    const float* W = P.w[layer * 4 + mtx];
    const float v = (k < Kd) ? W[(size_t)k * 128 + cc] : 0.f;
    Wt16[t] = (_Float16)v;
}

// ---------------------------------------------------------------------------
// MFMA GEMM v11: R13 swapped-operand structure.  Block pairing CHANGED to
// mp=0 -> {K->EK fp16, S->fp16} and mp=1 -> {Q->EQ8, V->V8} so one block
// produces both fp8 halves and writes them INTERLEAVED into QV8
// (uint2 per 4-col quad: {eq4, v4}) -- agg then gathers 16B per lane-edge
// instead of two 8B loads from separate arrays.
// ---------------------------------------------------------------------------
__global__ __launch_bounds__(256, 5) void gemm_mfma(
    const _Float16* __restrict__ A16, const _Float16* __restrict__ Wt16,
    const float* __restrict__ bias0, const float* __restrict__ bias1,
    const float* __restrict__ bias2, const float* __restrict__ bias3,
    _Float16* __restrict__ OEK, unsigned char* __restrict__ QV8,
    _Float16* __restrict__ OS, int M)
{
    __shared__ _Float16 ldsA[2][64 * 64];  // [k-half][row*64 + slot*8], 16KB
    const int t = threadIdx.x;
    const int l = t & 63, wc = t >> 6;
    const int row0 = blockIdx.x * 64;
    const int mp = blockIdx.y;             // 0: {K,S}  1: {Q,V}
    const int fr = l & 15;
    const int kq = l >> 4;

    #pragma unroll
    for (int i = 0; i < 4; ++i) {
        const int gi = i * 256 + t;        // 0..1023
        const int kh = gi >> 9;
        const int r = (gi >> 3) & 63;
        const int j = gi & 7;
        const int slot = j ^ (r & 7);
        *(half8v*)&ldsA[kh][r * 64 + slot * 8] =
            *(const half8v*)&A16[(size_t)(row0 + r) * 128 + kh * 64 + j * 8];
    }
    __syncthreads();   // the only barrier

    int p_eq[2][4];    // stash of packed fp8 EQ (mp==1, mi==0)

    #pragma unroll
    for (int mi = 0; mi < 2; ++mi) {
        const int mtx = (mp == 0) ? (mi == 0 ? 0 : 3) : (mi == 0 ? 1 : 2);
        f32x4 acc[4][2] = {};
        #pragma unroll
        for (int step = 0; step < 4; ++step) {
            const int kg = step * 4 + kq;
            const int kh = kg >> 3, kk = kg & 7;
            half8v a[4];
            #pragma unroll
            for (int m = 0; m < 4; ++m) {
                const int ar = m * 16 + fr;
                const int slot = kk ^ (ar & 7);
                a[m] = *(const half8v*)&ldsA[kh][ar * 64 + slot * 8];
            }
            half8v w[2];
            #pragma unroll
            for (int n = 0; n < 2; ++n) {
                const size_t wo = (size_t)(mtx * 128 + wc * 32 + n * 16 + fr) * 128 + kg * 8;
                w[n] = *(const half8v*)&Wt16[wo];
            }
            #pragma unroll
            for (int m = 0; m < 4; ++m)
                #pragma unroll
                for (int n = 0; n < 2; ++n)
                    acc[m][n] = __builtin_amdgcn_mfma_f32_16x16x32_f16(w[n], a[m], acc[m][n], 0, 0, 0);
        }
        const float* bias = (mtx == 0) ? bias0 : (mtx == 1) ? bias1
                          : (mtx == 2) ? bias2 : bias3;
        if (mp == 0) {
            if (mi == 0) {   // EK = fp16(exp(-K))
                #pragma unroll
                for (int n = 0; n < 2; ++n) {
                    const int c0 = wc * 32 + n * 16 + kq * 4;
                    const float4 bv = *(const float4*)&bias[c0];
                    #pragma unroll
                    for (int m = 0; m < 4; ++m) {
                        const int r = row0 + m * 16 + fr;
                        if (r < M) {
                            half4v o;
                            o[0] = (_Float16)__expf(-(acc[m][n][0] + bv.x));
                            o[1] = (_Float16)__expf(-(acc[m][n][1] + bv.y));
                            o[2] = (_Float16)__expf(-(acc[m][n][2] + bv.z));
                            o[3] = (_Float16)__expf(-(acc[m][n][3] + bv.w));
                            *(half4v*)&OEK[(size_t)r * 128 + c0] = o;
                        }
                    }
                }
            } else {         // S (skip) fp16
                #pragma unroll
                for (int n = 0; n < 2; ++n) {
                    const int c0 = wc * 32 + n * 16 + kq * 4;
                    const float4 bv = *(const float4*)&bias[c0];
                    #pragma unroll
                    for (int m = 0; m < 4; ++m) {
                        const int r = row0 + m * 16 + fr;
                        if (r < M) {
                            half4v o;
                            o[0] = (_Float16)(acc[m][n][0] + bv.x);
                            o[1] = (_Float16)(acc[m][n][1] + bv.y);
                            o[2] = (_Float16)(acc[m][n][2] + bv.z);
                            o[3] = (_Float16)(acc[m][n][3] + bv.w);
                            *(half4v*)&OS[(size_t)r * 128 + c0] = o;
                        }
                    }
                }
            }
        } else {
            if (mi == 0) {   // stash EQ8 = fp8(exp(-Q))
                #pragma unroll
                for (int n = 0; n < 2; ++n) {
                    const int c0 = wc * 32 + n * 16 + kq * 4;
                    const float4 bv = *(const float4*)&bias[c0];
                    #pragma unroll
                    for (int m = 0; m < 4; ++m) {
                        const float e0 = __expf(-(acc[m][n][0] + bv.x));
                        const float e1 = __expf(-(acc[m][n][1] + bv.y));
                        const float e2 = __expf(-(acc[m][n][2] + bv.z));
                        const float e3 = __expf(-(acc[m][n][3] + bv.w));
                        int p = 0;
                        p = __builtin_amdgcn_cvt_pk_fp8_f32(e0, e1, p, false);
                        p = __builtin_amdgcn_cvt_pk_fp8_f32(e2, e3, p, true);
                        p_eq[n][m] = p;
                    }
                }
            } else {         // V fp8 + combined {eq4, v4} store
                #pragma unroll
                for (int n = 0; n < 2; ++n) {
                    const int c0 = wc * 32 + n * 16 + kq * 4;
                    const float4 bv = *(const float4*)&bias[c0];
                    #pragma unroll
                    for (int m = 0; m < 4; ++m) {
                        const int r = row0 + m * 16 + fr;
                        int p = 0;
                        p = __builtin_amdgcn_cvt_pk_fp8_f32(acc[m][n][0] + bv.x,
                                                            acc[m][n][1] + bv.y, p, false);
                        p = __builtin_amdgcn_cvt_pk_fp8_f32(acc[m][n][2] + bv.z,
                                                            acc[m][n][3] + bv.w, p, true);
                        if (r < M) {
                            uint2 o;
                            o.x = (unsigned)p_eq[n][m];
                            o.y = (unsigned)p;
                            *(uint2*)&QV8[(size_t)r * 256 + (c0 / 4) * 8] = o;
                        }
                    }
                }
            }
        }
    }
}

// ---------------------------------------------------------------------------
// Atomic-free CSR build, two-phase bucket sort.
// Phase A: partition edges into 196 coarse buckets (dst>>8) -- per-block LDS
// hist, global scan, LDS-cursor scatter of packed (dst<<16|src).
// Phase B: one block per bucket builds fine CSR + off[] in LDS, contiguous
// writes (no fabric atomics, no cross-XCD line ping-pong).
// ---------------------------------------------------------------------------
__global__ __launch_bounds__(256) void pA_hist(const int* __restrict__ ei,
                                               int* __restrict__ ghA)
{
    __shared__ int lh[NBKT];
    const int t = threadIdx.x, b = blockIdx.x;
    if (t < NBKT) lh[t] = 0;
    __syncthreads();
    const int e0 = b * CHA;
    for (int i = t; i < CHA; i += 256)
        atomicAdd(&lh[ei[N_EDGES + e0 + i] >> 8], 1);
    __syncthreads();
    if (t < NBKT) ghA[t * NBA + b] = lh[t];
}

__global__ __launch_bounds__(1024) void pA_scan(int* __restrict__ g)
{
    __shared__ int part[1024];
    const int t = threadIdx.x;
    const int NT = NBKT * NBA;   // 19600
    const int CH = 20;
    const int base = t * CH;
    int s = 0;
    for (int i = 0; i < CH; ++i) {
        const int idx = base + i;
        if (idx < NT) s += g[idx];
    }
    part[t] = s;
    __syncthreads();
    for (int d = 1; d < 1024; d <<= 1) {
        const int v = (t >= d) ? part[t - d] : 0;
        __syncthreads();
        part[t] += v;
        __syncthreads();
    }
    int run = (t == 0) ? 0 : part[t - 1];
    for (int i = 0; i < CH; ++i) {
        const int idx = base + i;
        if (idx < NT) { const int c = g[idx]; g[idx] = run; run += c; }
    }
    if (t == 1023) g[NT] = part[1023];   // sentinel = E
}

__global__ __launch_bounds__(256) void pA_scat(const int* __restrict__ ei,
                                               const int* __restrict__ gbase,
                                               unsigned int* __restrict__ ebuf)
{
    __shared__ int cur[NBKT];
    const int t = threadIdx.x, b = blockIdx.x;
    if (t < NBKT) cur[t] = gbase[t * NBA + b];
    __syncthreads();
    const int e0 = b * CHA;
    for (int i = t; i < CHA; i += 256) {
        const unsigned d = (unsigned)ei[N_EDGES + e0 + i];
        const unsigned s = (unsigned)ei[e0 + i];
        const int pos = atomicAdd(&cur[d >> 8], 1);
        ebuf[pos] = (d << 16) | s;
    }
}

__global__ __launch_bounds__(256) void pB_build(const unsigned int* __restrict__ ebuf,
                                                const int* __restrict__ gbase,
                                                int* __restrict__ off,
                                                int* __restrict__ csr)
{
    __shared__ int lh[256], sc[256];
    const int t = threadIdx.x, b = blockIdx.x;
    const int beg = gbase[b * NBA];
    const int end = gbase[(b + 1) * NBA];
    lh[t] = 0;
    __syncthreads();
    for (int i = beg + t; i < end; i += 256)
        atomicAdd(&lh[(ebuf[i] >> 16) & 255], 1);
    __syncthreads();
    const int c = lh[t];
    sc[t] = c;
    __syncthreads();
    for (int d = 1; d < 256; d <<= 1) {
        const int v = (t >= d) ? sc[t - d] : 0;
        __syncthreads();
        sc[t] += v;
        __syncthreads();
    }
    const int excl = sc[t] - c;
    const int nd = b * 256 + t;
    if (nd <= N_NODES) off[nd] = beg + excl;
    __syncthreads();
    lh[t] = beg + excl;   // cursor
    __syncthreads();
    for (int i = beg + t; i < end; i += 256) {
        const unsigned p = ebuf[i];
        const int pos = atomicAdd(&lh[(p >> 16) & 255], 1);
        csr[pos] = (int)(p & 0xFFFFu);
    }
}

// ---------------------------------------------------------------------------
// CSR aggregation v8: one 16B QV8 gather per lane-edge ({eq4,v4} x 2 quads),
// fp16 EK; gate = rcp(1 + ek*eq).
// ---------------------------------------------------------------------------
template<int FUSE>
__global__ __launch_bounds__(256) void agg_csr(
    const _Float16* __restrict__ EKb, const unsigned char* __restrict__ QV8,
    const int* __restrict__ off, const int* __restrict__ csr_src,
    _Float16* __restrict__ hSkip, _Float16* __restrict__ A16, int Nn)
{
    const int node = blockIdx.x * 4 + (threadIdx.x >> 6);
    if (node >= Nn) return;
    const int lane = threadIdx.x & 63;
    const int grp = lane >> 4;
    const int sub = lane & 15;
    const int q = sub * 8;

    const half8v ek8 = *(const half8v*)(EKb + (size_t)node * H + q);
    float ek[8];
    #pragma unroll
    for (int i = 0; i < 8; ++i) ek[i] = (float)ek8[i];
    float acc[8] = {};

    const int begin = off[node], end = off[node + 1];
    for (int j0 = begin; j0 < end; j0 += 64) {
        const int nrem = end - j0;
        const int nk = nrem < 64 ? nrem : 64;
        const int sv = (lane < nk) ? csr_src[j0 + lane] : 0;
        #pragma unroll 4
        for (int k = 0; k < nk; k += 4) {
            const int myk = k + grp;
            const int s = __shfl(sv, myk < nk ? myk : 0);
            if (myk < nk) {
                const uint4 p = *(const uint4*)(QV8 + (size_t)s * 256 + sub * 16);
                const f32x2 ea = __builtin_amdgcn_cvt_pk_f32_fp8(p.x, false);
                const f32x2 eb = __builtin_amdgcn_cvt_pk_f32_fp8(p.x, true);
                const f32x2 va = __builtin_amdgcn_cvt_pk_f32_fp8(p.y, false);
                const f32x2 vb = __builtin_amdgcn_cvt_pk_f32_fp8(p.y, true);
                const f32x2 ec = __builtin_amdgcn_cvt_pk_f32_fp8(p.z, false);
                const f32x2 ed = __builtin_amdgcn_cvt_pk_f32_fp8(p.z, true);
                const f32x2 vc = __builtin_amdgcn_cvt_pk_f32_fp8(p.w, false);
                const f32x2 vd = __builtin_amdgcn_cvt_pk_f32_fp8(p.w, true);
                acc[0] = fmaf(va[0], __builtin_amdgcn_rcpf(fmaf(ek[0], ea[0], 1.f)), acc[0]);
                acc[1] = fmaf(va[1], __builtin_amdgcn_rcpf(fmaf(ek[1], ea[1], 1.f)), acc[1]);
                acc[2] = fmaf(vb[0], __builtin_amdgcn_rcpf(fmaf(ek[2], eb[0], 1.f)), acc[2]);
                acc[3] = fmaf(vb[1], __builtin_amdgcn_rcpf(fmaf(ek[3], eb[1], 1.f)), acc[3]);
                acc[4] = fmaf(vc[0], __builtin_amdgcn_rcpf(fmaf(ek[4], ec[0], 1.f)), acc[4]);
                acc[5] = fmaf(vc[1], __builtin_amdgcn_rcpf(fmaf(ek[5], ec[1], 1.f)), acc[5]);
                acc[6] = fmaf(vd[0], __builtin_amdgcn_rcpf(fmaf(ek[6], ed[0], 1.f)), acc[6]);
                acc[7] = fmaf(vd[1], __builtin_amdgcn_rcpf(fmaf(ek[7], ed[1], 1.f)), acc[7]);
            }
        }
    }
    #pragma unroll
    for (int i = 0; i < 8; ++i) {
        acc[i] += __shfl_xor(acc[i], 16);
        acc[i] += __shfl_xor(acc[i], 32);
    }
    if (grp == 0) {
        const half8v sk8 = *(const half8v*)(hSkip + (size_t)node * H + q);
        half8v hv;
        if (FUSE) {
            #pragma unroll
            for (int j = 0; j < 8; ++j)
                hv[j] = (_Float16)fmaxf((float)sk8[j] + acc[j], 0.f);
            *(half8v*)&A16[(size_t)node * 128 + q] = hv;
        } else {
            #pragma unroll
            for (int j = 0; j < 8; ++j)
                hv[j] = (_Float16)((float)sk8[j] + acc[j]);
            *(half8v*)&hSkip[(size_t)node * H + q] = hv;
        }
    }
}

// ---------------------------------------------------------------------------
// Pool (fp16 h) + MLP
// ---------------------------------------------------------------------------
__global__ __launch_bounds__(256) void gstart_kernel(const int* __restrict__ batch,
                                                     int* __restrict__ gstart, int Nn)
{
    const int n = blockIdx.x * 256 + threadIdx.x;
    if (n >= Nn) return;
    const int b = batch[n];
    const int bp = (n == 0) ? -1 : batch[n - 1];
    for (int g = bp + 1; g <= b; ++g) gstart[g] = n;
    if (n == Nn - 1)
        for (int g = b + 1; g <= N_GRAPHS; ++g) gstart[g] = Nn;
}

__global__ __launch_bounds__(128) void pool_seg(const _Float16* __restrict__ h,
                                                const int* __restrict__ gstart,
                                                float* __restrict__ hg)
{
    const int g = blockIdx.x;
    const int part = blockIdx.y;
    const int t = threadIdx.x;
    const int b0 = gstart[g], b1 = gstart[g + 1];
    float acc = 0.f;
    for (int n = b0 + part; n < b1; n += 4) acc += (float)h[(size_t)n * H + t];
    atomicAdd(&hg[(size_t)g * H + t], acc);
}

__global__ __launch_bounds__(64) void mlp_kernel(
    const float* __restrict__ hg,
    const float* __restrict__ W4, const float* __restrict__ b4,
    const float* __restrict__ W5, const float* __restrict__ b5,
    float* __restrict__ out)
{
    const int g = blockIdx.x;
    const int c = threadIdx.x;
    __shared__ float hrow[H];
    for (int k = c; k < H; k += 64) hrow[k] = hg[(size_t)g * H + k];
    __syncthreads();
    float s = b4[c];
    #pragma unroll 8
    for (int k = 0; k < H; ++k) s += hrow[k] * W4[(size_t)k * 64 + c];
    s = fmaxf(s, 0.f) * W5[c];
    #pragma unroll
    for (int off = 32; off > 0; off >>= 1) s += __shfl_down(s, off);
    if (c == 0) out[g] = 1.f / (1.f + __expf(-(s + b5[0])));
}

// ---------------------------------------------------------------------------
extern "C" void kernel_launch(void* const* d_in, const int* in_sizes, int n_in,
                              void* d_out, int out_size, void* d_ws, size_t ws_size,
                              hipStream_t stream)
{
    const float* x = (const float*)d_in[0];
    const float *Wk[3], *bk[3], *Wq[3], *bq[3], *Wv[3], *bv[3], *Wsk[3], *bs[3];
    for (int l = 0; l < 3; ++l) {
        const int base = 2 + l * 8;
        Wk[l]  = (const float*)d_in[base + 0]; bk[l] = (const float*)d_in[base + 1];
        Wq[l]  = (const float*)d_in[base + 2]; bq[l] = (const float*)d_in[base + 3];
        Wv[l]  = (const float*)d_in[base + 4]; bv[l] = (const float*)d_in[base + 5];
        Wsk[l] = (const float*)d_in[base + 6]; bs[l] = (const float*)d_in[base + 7];
    }
    const float* W4 = (const float*)d_in[26];
    const float* b4 = (const float*)d_in[27];
    const float* W5 = (const float*)d_in[28];
    const float* b5 = (const float*)d_in[29];
    const int* ei    = (const int*)d_in[30];
    const int* batch = (const int*)d_in[31];
    float* out = (float*)d_out;

    const size_t NH = (size_t)N_NODES * H;
    const size_t AH = (size_t)MP * 128;
    const size_t WH3 = (size_t)3 * 512 * 128;
    _Float16*      EKb  = (_Float16*)d_ws;                    // NH halfs
    _Float16*      hbuf = EKb + NH;                           // NH halfs
    unsigned char* QV8  = (unsigned char*)(hbuf + NH);        // 2*NH bytes
    _Float16*      A16  = (_Float16*)(QV8 + 2 * NH);          // AH halfs
    _Float16*      Wt16 = A16 + AH;                           // WH3 halfs
    float*         hg   = (float*)(Wt16 + WH3);               // G*H (zeroed)
    int*           off  = (int*)(hg + (size_t)N_GRAPHS * H);  // N+1
    int*           csr  = off + (N_NODES + 1);                // E
    unsigned int*  ebuf = (unsigned int*)(csr + N_EDGES);     // E
    int*           ghA  = (int*)(ebuf + N_EDGES);             // NBKT*NBA+1
    int*           gst  = ghA + (NBKT * NBA + 1);             // G+1
    const size_t need = (size_t)N_GRAPHS * H * sizeof(float)
                      + 2 * NH * sizeof(unsigned char)
                      + (2 * NH + AH + WH3) * sizeof(_Float16)
                      + (size_t)(N_NODES + 1 + 2 * N_EDGES + NBKT * NBA + 1
                                 + N_GRAPHS + 1) * sizeof(int);
    if (ws_size < need) return;

    const int ablk = (N_NODES + 3) / 4;
    const int nblk = (N_NODES + 255) / 256;
    const int cablk = (MP * 16) / 256;
    const dim3 ggrid(MP / 64, 2);        // 782 x 2 = 1564 blocks
    const dim3 pgrid(N_GRAPHS, 4);

    // ---- memset: hg only (CSR build writes all its outputs)
    hipMemsetAsync(hg, 0, (size_t)N_GRAPHS * H * sizeof(float), stream);

    // ---- atomic-free CSR build + graph segments + weight conversion
    pA_hist<<<NBA, 256, 0, stream>>>(ei, ghA);
    pA_scan<<<1, 1024, 0, stream>>>(ghA);
    pA_scat<<<NBA, 256, 0, stream>>>(ei, ghA, ebuf);
    pB_build<<<NBKT, 256, 0, stream>>>(ebuf, ghA, off, csr);
    gstart_kernel<<<nblk, 256, 0, stream>>>(batch, gst, N_NODES);
    WPtrs wp;
    for (int l = 0; l < 3; ++l) {
        wp.w[l * 4 + 0] = Wk[l];
        wp.w[l * 4 + 1] = Wq[l];
        wp.w[l * 4 + 2] = Wv[l];
        wp.w[l * 4 + 3] = Wsk[l];
    }
    conv_W3<<<768, 256, 0, stream>>>(wp, Wt16);

    // ---- Layer 1
    conv_A<<<cablk, 256, 0, stream>>>(x, N_NODES, DIN, A16);
    gemm_mfma<<<ggrid, 256, 0, stream>>>(A16, Wt16,
        bk[0], bq[0], bv[0], bs[0], EKb, QV8, hbuf, N_NODES);
    agg_csr<1><<<ablk, 256, 0, stream>>>(EKb, QV8, off, csr, hbuf, A16, N_NODES);

    // ---- Layer 2
    gemm_mfma<<<ggrid, 256, 0, stream>>>(A16, Wt16 + 512 * 128,
        bk[1], bq[1], bv[1], bs[1], EKb, QV8, hbuf, N_NODES);
    agg_csr<1><<<ablk, 256, 0, stream>>>(EKb, QV8, off, csr, hbuf, A16, N_NODES);

    // ---- Layer 3
    gemm_mfma<<<ggrid, 256, 0, stream>>>(A16, Wt16 + 1024 * 128,
        bk[2], bq[2], bv[2], bs[2], EKb, QV8, hbuf, N_NODES);
    agg_csr<0><<<ablk, 256, 0, stream>>>(EKb, QV8, off, csr, hbuf, A16, N_NODES);

    // ---- Pool + MLP
    pool_seg<<<pgrid, 128, 0, stream>>>(hbuf, gst, hg);
    mlp_kernel<<<N_GRAPHS, 64, 0, stream>>>(hg, W4, b4, W5, b5, out);
}

// Round 17
// 318.454 us; speedup vs baseline: 1.6353x; 1.0694x over previous
//
#include <hip/hip_runtime.h>

#define N_NODES 50000
#define N_EDGES 800000
#define N_GRAPHS 256
#define DIN 126
#define H 128
#define MP 50048           // N_NODES padded to 128
#define NBKT 196           // coarse buckets = dst>>8
#define NBA 100            // phase-A blocks
#define CHA 8000           // edges per phase-A block

typedef __attribute__((ext_vector_type(8))) _Float16 half8v;
typedef __attribute__((ext_vector_type(4))) _Float16 half4v;
typedef __attribute__((ext_vector_type(4))) float f32x4;
typedef __attribute__((ext_vector_type(2))) float f32x2;

// ---------------------------------------------------------------------------
// A conversion (layer-1 input only): X fp32 [M,Kd] -> A16 fp16 [MP][128]
// ---------------------------------------------------------------------------
__global__ __launch_bounds__(256) void conv_A(const float* __restrict__ X, int M, int Kd,
                                              _Float16* __restrict__ A16)
{
    const int t = blockIdx.x * 256 + threadIdx.x;
    const int row = t >> 4;
    if (row >= MP) return;
    const int k0 = (t & 15) * 8;
    half8v v8;
    #pragma unroll
    for (int j = 0; j < 8; ++j) {
        const int k = k0 + j;
        float v = 0.f;
        if (row < M && k < Kd) v = X[(size_t)row * Kd + k];
        v8[j] = (_Float16)v;
    }
    *(half8v*)&A16[(size_t)row * 128 + k0] = v8;
}

// ---------------------------------------------------------------------------
// W conversion, all 3 layers in one launch.
// ---------------------------------------------------------------------------
struct WPtrs { const float* w[12]; };

__global__ __launch_bounds__(256) void conv_W3(WPtrs P, _Float16* __restrict__ Wt16)
{
    const int t = blockIdx.x * 256 + threadIdx.x;
    if (t >= 3 * 512 * 128) return;
    const int layer = t >> 16;
    const int r = t & 65535;
    const int n = r >> 7, k = r & 127;
    const int mtx = n >> 7, cc = n & 127;
    const int Kd = (layer == 0) ? DIN : H;
    const float* W = P.w[layer * 4 + mtx];
    const float v = (k < Kd) ? W[(size_t)k * 128 + cc] : 0.f;
    Wt16[t] = (_Float16)v;
}

// ---------------------------------------------------------------------------
// MFMA GEMM v12: R16 structure + LDS-staged DENSE epilogue stores.
// Each lane deposits 8B pieces into ldsO[64][32] (quad swizzle qd^fr), then a
// dense pass writes full 256B rows with 16B/lane coalesced uint4 stores --
// kills the 2.7x partial-line write amplification (agg's dense rows = 1:1).
// All output buffers have 256B row pitch (EK fp16, S fp16, QV8 bytes).
// ---------------------------------------------------------------------------
__device__ __forceinline__ void dense_out(const uint2 (&ldsO)[64][32],
                                          unsigned char* __restrict__ dst,
                                          int row0, int M, int t)
{
    #pragma unroll
    for (int i = 0; i < 4; ++i) {
        const int idx = i * 256 + t;            // 0..1023
        const int rr = idx >> 4, c16 = idx & 15;
        const int ch = c16 ^ ((rr & 15) >> 1);  // physical 16B chunk
        const uint2 a = ldsO[rr][2 * ch];
        const uint2 b = ldsO[rr][2 * ch + 1];
        if (row0 + rr < M) {
            uint4 o;
            if (rr & 1) { o.x = b.x; o.y = b.y; o.z = a.x; o.w = a.y; }
            else        { o.x = a.x; o.y = a.y; o.z = b.x; o.w = b.y; }
            *(uint4*)(dst + (size_t)(row0 + rr) * 256 + c16 * 16) = o;
        }
    }
}

__device__ __forceinline__ void compute_acc(const _Float16 (&ldsA)[2][64 * 64],
                                            const _Float16* __restrict__ Wt16,
                                            int mtx, int fr, int kq, int wc,
                                            f32x4 (&acc)[4][2])
{
    #pragma unroll
    for (int step = 0; step < 4; ++step) {
        const int kg = step * 4 + kq;
        const int kh = kg >> 3, kk = kg & 7;
        half8v a[4];
        #pragma unroll
        for (int m = 0; m < 4; ++m) {
            const int ar = m * 16 + fr;
            const int slot = kk ^ (ar & 7);
            a[m] = *(const half8v*)&ldsA[kh][ar * 64 + slot * 8];
        }
        half8v w[2];
        #pragma unroll
        for (int n = 0; n < 2; ++n) {
            const size_t wo = (size_t)(mtx * 128 + wc * 32 + n * 16 + fr) * 128 + kg * 8;
            w[n] = *(const half8v*)&Wt16[wo];
        }
        #pragma unroll
        for (int m = 0; m < 4; ++m)
            #pragma unroll
            for (int n = 0; n < 2; ++n)
                acc[m][n] = __builtin_amdgcn_mfma_f32_16x16x32_f16(w[n], a[m], acc[m][n], 0, 0, 0);
    }
}

__global__ __launch_bounds__(256, 5) void gemm_mfma(
    const _Float16* __restrict__ A16, const _Float16* __restrict__ Wt16,
    const float* __restrict__ bias0, const float* __restrict__ bias1,
    const float* __restrict__ bias2, const float* __restrict__ bias3,
    _Float16* __restrict__ OEK, unsigned char* __restrict__ QV8,
    _Float16* __restrict__ OS, int M)
{
    __shared__ _Float16 ldsA[2][64 * 64];  // 16KB
    __shared__ uint2 ldsO[64][32];         // 16KB: 64 rows x 32 8B-quads
    const int t = threadIdx.x;
    const int l = t & 63, wc = t >> 6;
    const int row0 = blockIdx.x * 64;
    const int mp = blockIdx.y;             // 0: {K,S}  1: {Q,V}
    const int fr = l & 15;
    const int kq = l >> 4;

    #pragma unroll
    for (int i = 0; i < 4; ++i) {
        const int gi = i * 256 + t;        // 0..1023
        const int kh = gi >> 9;
        const int r = (gi >> 3) & 63;
        const int j = gi & 7;
        const int slot = j ^ (r & 7);
        *(half8v*)&ldsA[kh][r * 64 + slot * 8] =
            *(const half8v*)&A16[(size_t)(row0 + r) * 128 + kh * 64 + j * 8];
    }
    __syncthreads();

    if (mp == 0) {
        // ---- K -> EK = fp16(exp(-K))
        {
            f32x4 acc[4][2] = {};
            compute_acc(ldsA, Wt16, 0, fr, kq, wc, acc);
            #pragma unroll
            for (int n = 0; n < 2; ++n) {
                const int c0 = wc * 32 + n * 16 + kq * 4;
                const float4 bv = *(const float4*)&bias0[c0];
                #pragma unroll
                for (int m = 0; m < 4; ++m) {
                    const int rl = m * 16 + fr;
                    half4v o;
                    o[0] = (_Float16)__expf(-(acc[m][n][0] + bv.x));
                    o[1] = (_Float16)__expf(-(acc[m][n][1] + bv.y));
                    o[2] = (_Float16)__expf(-(acc[m][n][2] + bv.z));
                    o[3] = (_Float16)__expf(-(acc[m][n][3] + bv.w));
                    ldsO[rl][(c0 >> 2) ^ fr] = *(uint2*)&o;
                }
            }
        }
        __syncthreads();
        dense_out(ldsO, (unsigned char*)OEK, row0, M, t);
        __syncthreads();
        // ---- S (skip) fp16
        {
            f32x4 acc[4][2] = {};
            compute_acc(ldsA, Wt16, 3, fr, kq, wc, acc);
            #pragma unroll
            for (int n = 0; n < 2; ++n) {
                const int c0 = wc * 32 + n * 16 + kq * 4;
                const float4 bv = *(const float4*)&bias3[c0];
                #pragma unroll
                for (int m = 0; m < 4; ++m) {
                    const int rl = m * 16 + fr;
                    half4v o;
                    o[0] = (_Float16)(acc[m][n][0] + bv.x);
                    o[1] = (_Float16)(acc[m][n][1] + bv.y);
                    o[2] = (_Float16)(acc[m][n][2] + bv.z);
                    o[3] = (_Float16)(acc[m][n][3] + bv.w);
                    ldsO[rl][(c0 >> 2) ^ fr] = *(uint2*)&o;
                }
            }
        }
        __syncthreads();
        dense_out(ldsO, (unsigned char*)OS, row0, M, t);
    } else {
        // ---- Q -> EQ8 = fp8(exp(-Q)) into low 4B of each quad
        {
            f32x4 acc[4][2] = {};
            compute_acc(ldsA, Wt16, 1, fr, kq, wc, acc);
            #pragma unroll
            for (int n = 0; n < 2; ++n) {
                const int c0 = wc * 32 + n * 16 + kq * 4;
                const float4 bv = *(const float4*)&bias1[c0];
                #pragma unroll
                for (int m = 0; m < 4; ++m) {
                    const int rl = m * 16 + fr;
                    const float e0 = __expf(-(acc[m][n][0] + bv.x));
                    const float e1 = __expf(-(acc[m][n][1] + bv.y));
                    const float e2 = __expf(-(acc[m][n][2] + bv.z));
                    const float e3 = __expf(-(acc[m][n][3] + bv.w));
                    int p = 0;
                    p = __builtin_amdgcn_cvt_pk_fp8_f32(e0, e1, p, false);
                    p = __builtin_amdgcn_cvt_pk_fp8_f32(e2, e3, p, true);
                    ((unsigned*)&ldsO[rl][(c0 >> 2) ^ fr])[0] = (unsigned)p;
                }
            }
        }
        // ---- V -> fp8 into high 4B (same lane, same quad: no race)
        {
            f32x4 acc[4][2] = {};
            compute_acc(ldsA, Wt16, 2, fr, kq, wc, acc);
            #pragma unroll
            for (int n = 0; n < 2; ++n) {
                const int c0 = wc * 32 + n * 16 + kq * 4;
                const float4 bv = *(const float4*)&bias2[c0];
                #pragma unroll
                for (int m = 0; m < 4; ++m) {
                    const int rl = m * 16 + fr;
                    int p = 0;
                    p = __builtin_amdgcn_cvt_pk_fp8_f32(acc[m][n][0] + bv.x,
                                                        acc[m][n][1] + bv.y, p, false);
                    p = __builtin_amdgcn_cvt_pk_fp8_f32(acc[m][n][2] + bv.z,
                                                        acc[m][n][3] + bv.w, p, true);
                    ((unsigned*)&ldsO[rl][(c0 >> 2) ^ fr])[1] = (unsigned)p;
                }
            }
        }
        __syncthreads();
        dense_out(ldsO, QV8, row0, M, t);
    }
}

// ---------------------------------------------------------------------------
// Atomic-free CSR build (unchanged from R16)
// ---------------------------------------------------------------------------
__global__ __launch_bounds__(256) void pA_hist(const int* __restrict__ ei,
                                               int* __restrict__ ghA)
{
    __shared__ int lh[NBKT];
    const int t = threadIdx.x, b = blockIdx.x;
    if (t < NBKT) lh[t] = 0;
    __syncthreads();
    const int e0 = b * CHA;
    for (int i = t; i < CHA; i += 256)
        atomicAdd(&lh[ei[N_EDGES + e0 + i] >> 8], 1);
    __syncthreads();
    if (t < NBKT) ghA[t * NBA + b] = lh[t];
}

__global__ __launch_bounds__(1024) void pA_scan(int* __restrict__ g)
{
    __shared__ int part[1024];
    const int t = threadIdx.x;
    const int NT = NBKT * NBA;
    const int CH = 20;
    const int base = t * CH;
    int s = 0;
    for (int i = 0; i < CH; ++i) {
        const int idx = base + i;
        if (idx < NT) s += g[idx];
    }
    part[t] = s;
    __syncthreads();
    for (int d = 1; d < 1024; d <<= 1) {
        const int v = (t >= d) ? part[t - d] : 0;
        __syncthreads();
        part[t] += v;
        __syncthreads();
    }
    int run = (t == 0) ? 0 : part[t - 1];
    for (int i = 0; i < CH; ++i) {
        const int idx = base + i;
        if (idx < NT) { const int c = g[idx]; g[idx] = run; run += c; }
    }
    if (t == 1023) g[NT] = part[1023];
}

__global__ __launch_bounds__(256) void pA_scat(const int* __restrict__ ei,
                                               const int* __restrict__ gbase,
                                               unsigned int* __restrict__ ebuf)
{
    __shared__ int cur[NBKT];
    const int t = threadIdx.x, b = blockIdx.x;
    if (t < NBKT) cur[t] = gbase[t * NBA + b];
    __syncthreads();
    const int e0 = b * CHA;
    for (int i = t; i < CHA; i += 256) {
        const unsigned d = (unsigned)ei[N_EDGES + e0 + i];
        const unsigned s = (unsigned)ei[e0 + i];
        const int pos = atomicAdd(&cur[d >> 8], 1);
        ebuf[pos] = (d << 16) | s;
    }
}

__global__ __launch_bounds__(256) void pB_build(const unsigned int* __restrict__ ebuf,
                                                const int* __restrict__ gbase,
                                                int* __restrict__ off,
                                                int* __restrict__ csr)
{
    __shared__ int lh[256], sc[256];
    const int t = threadIdx.x, b = blockIdx.x;
    const int beg = gbase[b * NBA];
    const int end = gbase[(b + 1) * NBA];
    lh[t] = 0;
    __syncthreads();
    for (int i = beg + t; i < end; i += 256)
        atomicAdd(&lh[(ebuf[i] >> 16) & 255], 1);
    __syncthreads();
    const int c = lh[t];
    sc[t] = c;
    __syncthreads();
    for (int d = 1; d < 256; d <<= 1) {
        const int v = (t >= d) ? sc[t - d] : 0;
        __syncthreads();
        sc[t] += v;
        __syncthreads();
    }
    const int excl = sc[t] - c;
    const int nd = b * 256 + t;
    if (nd <= N_NODES) off[nd] = beg + excl;
    __syncthreads();
    lh[t] = beg + excl;
    __syncthreads();
    for (int i = beg + t; i < end; i += 256) {
        const unsigned p = ebuf[i];
        const int pos = atomicAdd(&lh[(p >> 16) & 255], 1);
        csr[pos] = (int)(p & 0xFFFFu);
    }
}

// ---------------------------------------------------------------------------
// CSR aggregation (unchanged from R16): 16B QV8 gathers, fp16 EK.
// ---------------------------------------------------------------------------
template<int FUSE>
__global__ __launch_bounds__(256) void agg_csr(
    const _Float16* __restrict__ EKb, const unsigned char* __restrict__ QV8,
    const int* __restrict__ off, const int* __restrict__ csr_src,
    _Float16* __restrict__ hSkip, _Float16* __restrict__ A16, int Nn)
{
    const int node = blockIdx.x * 4 + (threadIdx.x >> 6);
    if (node >= Nn) return;
    const int lane = threadIdx.x & 63;
    const int grp = lane >> 4;
    const int sub = lane & 15;
    const int q = sub * 8;

    const half8v ek8 = *(const half8v*)(EKb + (size_t)node * H + q);
    float ek[8];
    #pragma unroll
    for (int i = 0; i < 8; ++i) ek[i] = (float)ek8[i];
    float acc[8] = {};

    const int begin = off[node], end = off[node + 1];
    for (int j0 = begin; j0 < end; j0 += 64) {
        const int nrem = end - j0;
        const int nk = nrem < 64 ? nrem : 64;
        const int sv = (lane < nk) ? csr_src[j0 + lane] : 0;
        #pragma unroll 4
        for (int k = 0; k < nk; k += 4) {
            const int myk = k + grp;
            const int s = __shfl(sv, myk < nk ? myk : 0);
            if (myk < nk) {
                const uint4 p = *(const uint4*)(QV8 + (size_t)s * 256 + sub * 16);
                const f32x2 ea = __builtin_amdgcn_cvt_pk_f32_fp8(p.x, false);
                const f32x2 eb = __builtin_amdgcn_cvt_pk_f32_fp8(p.x, true);
                const f32x2 va = __builtin_amdgcn_cvt_pk_f32_fp8(p.y, false);
                const f32x2 vb = __builtin_amdgcn_cvt_pk_f32_fp8(p.y, true);
                const f32x2 ec = __builtin_amdgcn_cvt_pk_f32_fp8(p.z, false);
                const f32x2 ed = __builtin_amdgcn_cvt_pk_f32_fp8(p.z, true);
                const f32x2 vc = __builtin_amdgcn_cvt_pk_f32_fp8(p.w, false);
                const f32x2 vd = __builtin_amdgcn_cvt_pk_f32_fp8(p.w, true);
                acc[0] = fmaf(va[0], __builtin_amdgcn_rcpf(fmaf(ek[0], ea[0], 1.f)), acc[0]);
                acc[1] = fmaf(va[1], __builtin_amdgcn_rcpf(fmaf(ek[1], ea[1], 1.f)), acc[1]);
                acc[2] = fmaf(vb[0], __builtin_amdgcn_rcpf(fmaf(ek[2], eb[0], 1.f)), acc[2]);
                acc[3] = fmaf(vb[1], __builtin_amdgcn_rcpf(fmaf(ek[3], eb[1], 1.f)), acc[3]);
                acc[4] = fmaf(vc[0], __builtin_amdgcn_rcpf(fmaf(ek[4], ec[0], 1.f)), acc[4]);
                acc[5] = fmaf(vc[1], __builtin_amdgcn_rcpf(fmaf(ek[5], ec[1], 1.f)), acc[5]);
                acc[6] = fmaf(vd[0], __builtin_amdgcn_rcpf(fmaf(ek[6], ed[0], 1.f)), acc[6]);
                acc[7] = fmaf(vd[1], __builtin_amdgcn_rcpf(fmaf(ek[7], ed[1], 1.f)), acc[7]);
            }
        }
    }
    #pragma unroll
    for (int i = 0; i < 8; ++i) {
        acc[i] += __shfl_xor(acc[i], 16);
        acc[i] += __shfl_xor(acc[i], 32);
    }
    if (grp == 0) {
        const half8v sk8 = *(const half8v*)(hSkip + (size_t)node * H + q);
        half8v hv;
        if (FUSE) {
            #pragma unroll
            for (int j = 0; j < 8; ++j)
                hv[j] = (_Float16)fmaxf((float)sk8[j] + acc[j], 0.f);
            *(half8v*)&A16[(size_t)node * 128 + q] = hv;
        } else {
            #pragma unroll
            for (int j = 0; j < 8; ++j)
                hv[j] = (_Float16)((float)sk8[j] + acc[j]);
            *(half8v*)&hSkip[(size_t)node * H + q] = hv;
        }
    }
}

// ---------------------------------------------------------------------------
// Pool (fp16 h) + MLP (unchanged)
// ---------------------------------------------------------------------------
__global__ __launch_bounds__(256) void gstart_kernel(const int* __restrict__ batch,
                                                     int* __restrict__ gstart, int Nn)
{
    const int n = blockIdx.x * 256 + threadIdx.x;
    if (n >= Nn) return;
    const int b = batch[n];
    const int bp = (n == 0) ? -1 : batch[n - 1];
    for (int g = bp + 1; g <= b; ++g) gstart[g] = n;
    if (n == Nn - 1)
        for (int g = b + 1; g <= N_GRAPHS; ++g) gstart[g] = Nn;
}

__global__ __launch_bounds__(128) void pool_seg(const _Float16* __restrict__ h,
                                                const int* __restrict__ gstart,
                                                float* __restrict__ hg)
{
    const int g = blockIdx.x;
    const int part = blockIdx.y;
    const int t = threadIdx.x;
    const int b0 = gstart[g], b1 = gstart[g + 1];
    float acc = 0.f;
    for (int n = b0 + part; n < b1; n += 4) acc += (float)h[(size_t)n * H + t];
    atomicAdd(&hg[(size_t)g * H + t], acc);
}

__global__ __launch_bounds__(64) void mlp_kernel(
    const float* __restrict__ hg,
    const float* __restrict__ W4, const float* __restrict__ b4,
    const float* __restrict__ W5, const float* __restrict__ b5,
    float* __restrict__ out)
{
    const int g = blockIdx.x;
    const int c = threadIdx.x;
    __shared__ float hrow[H];
    for (int k = c; k < H; k += 64) hrow[k] = hg[(size_t)g * H + k];
    __syncthreads();
    float s = b4[c];
    #pragma unroll 8
    for (int k = 0; k < H; ++k) s += hrow[k] * W4[(size_t)k * 64 + c];
    s = fmaxf(s, 0.f) * W5[c];
    #pragma unroll
    for (int off = 32; off > 0; off >>= 1) s += __shfl_down(s, off);
    if (c == 0) out[g] = 1.f / (1.f + __expf(-(s + b5[0])));
}

// ---------------------------------------------------------------------------
extern "C" void kernel_launch(void* const* d_in, const int* in_sizes, int n_in,
                              void* d_out, int out_size, void* d_ws, size_t ws_size,
                              hipStream_t stream)
{
    const float* x = (const float*)d_in[0];
    const float *Wk[3], *bk[3], *Wq[3], *bq[3], *Wv[3], *bv[3], *Wsk[3], *bs[3];
    for (int l = 0; l < 3; ++l) {
        const int base = 2 + l * 8;
        Wk[l]  = (const float*)d_in[base + 0]; bk[l] = (const float*)d_in[base + 1];
        Wq[l]  = (const float*)d_in[base + 2]; bq[l] = (const float*)d_in[base + 3];
        Wv[l]  = (const float*)d_in[base + 4]; bv[l] = (const float*)d_in[base + 5];
        Wsk[l] = (const float*)d_in[base + 6]; bs[l] = (const float*)d_in[base + 7];
    }
    const float* W4 = (const float*)d_in[26];
    const float* b4 = (const float*)d_in[27];
    const float* W5 = (const float*)d_in[28];
    const float* b5 = (const float*)d_in[29];
    const int* ei    = (const int*)d_in[30];
    const int* batch = (const int*)d_in[31];
    float* out = (float*)d_out;

    const size_t NH = (size_t)N_NODES * H;
    const size_t AH = (size_t)MP * 128;
    const size_t WH3 = (size_t)3 * 512 * 128;
    _Float16*      EKb  = (_Float16*)d_ws;                    // NH halfs
    _Float16*      hbuf = EKb + NH;                           // NH halfs
    unsigned char* QV8  = (unsigned char*)(hbuf + NH);        // 2*NH bytes
    _Float16*      A16  = (_Float16*)(QV8 + 2 * NH);          // AH halfs
    _Float16*      Wt16 = A16 + AH;                           // WH3 halfs
    float*         hg   = (float*)(Wt16 + WH3);               // G*H (zeroed)
    int*           off  = (int*)(hg + (size_t)N_GRAPHS * H);  // N+1
    int*           csr  = off + (N_NODES + 1);                // E
    unsigned int*  ebuf = (unsigned int*)(csr + N_EDGES);     // E
    int*           ghA  = (int*)(ebuf + N_EDGES);             // NBKT*NBA+1
    int*           gst  = ghA + (NBKT * NBA + 1);             // G+1
    const size_t need = (size_t)N_GRAPHS * H * sizeof(float)
                      + 2 * NH * sizeof(unsigned char)
                      + (2 * NH + AH + WH3) * sizeof(_Float16)
                      + (size_t)(N_NODES + 1 + 2 * N_EDGES + NBKT * NBA + 1
                                 + N_GRAPHS + 1) * sizeof(int);
    if (ws_size < need) return;

    const int ablk = (N_NODES + 3) / 4;
    const int nblk = (N_NODES + 255) / 256;
    const int cablk = (MP * 16) / 256;
    const dim3 ggrid(MP / 64, 2);        // 782 x 2 = 1564 blocks
    const dim3 pgrid(N_GRAPHS, 4);

    // ---- memset: hg only
    hipMemsetAsync(hg, 0, (size_t)N_GRAPHS * H * sizeof(float), stream);

    // ---- atomic-free CSR build + graph segments + weight conversion
    pA_hist<<<NBA, 256, 0, stream>>>(ei, ghA);
    pA_scan<<<1, 1024, 0, stream>>>(ghA);
    pA_scat<<<NBA, 256, 0, stream>>>(ei, ghA, ebuf);
    pB_build<<<NBKT, 256, 0, stream>>>(ebuf, ghA, off, csr);
    gstart_kernel<<<nblk, 256, 0, stream>>>(batch, gst, N_NODES);
    WPtrs wp;
    for (int l = 0; l < 3; ++l) {
        wp.w[l * 4 + 0] = Wk[l];
        wp.w[l * 4 + 1] = Wq[l];
        wp.w[l * 4 + 2] = Wv[l];
        wp.w[l * 4 + 3] = Wsk[l];
    }
    conv_W3<<<768, 256, 0, stream>>>(wp, Wt16);

    // ---- Layer 1
    conv_A<<<cablk, 256, 0, stream>>>(x, N_NODES, DIN, A16);
    gemm_mfma<<<ggrid, 256, 0, stream>>>(A16, Wt16,
        bk[0], bq[0], bv[0], bs[0], EKb, QV8, hbuf, N_NODES);
    agg_csr<1><<<ablk, 256, 0, stream>>>(EKb, QV8, off, csr, hbuf, A16, N_NODES);

    // ---- Layer 2
    gemm_mfma<<<ggrid, 256, 0, stream>>>(A16, Wt16 + 512 * 128,
        bk[1], bq[1], bv[1], bs[1], EKb, QV8, hbuf, N_NODES);
    agg_csr<1><<<ablk, 256, 0, stream>>>(EKb, QV8, off, csr, hbuf, A16, N_NODES);

    // ---- Layer 3
    gemm_mfma<<<ggrid, 256, 0, stream>>>(A16, Wt16 + 1024 * 128,
        bk[2], bq[2], bv[2], bs[2], EKb, QV8, hbuf, N_NODES);
    agg_csr<0><<<ablk, 256, 0, stream>>>(EKb, QV8, off, csr, hbuf, A16, N_NODES);

    // ---- Pool + MLP
    pool_seg<<<pgrid, 128, 0, stream>>>(hbuf, gst, hg);
    mlp_kernel<<<N_GRAPHS, 64, 0, stream>>>(hg, W4, b4, W5, b5, out);
}

// Round 18
// 296.864 us; speedup vs baseline: 1.7542x; 1.0727x over previous
//
#include <hip/hip_runtime.h>

#define N_NODES 50000
#define N_EDGES 800000
#define N_GRAPHS 256
#define DIN 126
#define H 128
#define MP 50048           // N_NODES padded to 128
#define NBKT 196           // coarse buckets = dst>>8
#define NBA 100            // phase-A blocks
#define CHA 8000           // edges per phase-A block

typedef __attribute__((ext_vector_type(8))) _Float16 half8v;
typedef __attribute__((ext_vector_type(4))) _Float16 half4v;
typedef __attribute__((ext_vector_type(4))) float f32x4;
typedef __attribute__((ext_vector_type(2))) float f32x2;

// ---------------------------------------------------------------------------
// A conversion (layer-1 input only): X fp32 [M,Kd] -> A16 fp16 [MP][128]
// ---------------------------------------------------------------------------
__global__ __launch_bounds__(256) void conv_A(const float* __restrict__ X, int M, int Kd,
                                              _Float16* __restrict__ A16)
{
    const int t = blockIdx.x * 256 + threadIdx.x;
    const int row = t >> 4;
    if (row >= MP) return;
    const int k0 = (t & 15) * 8;
    half8v v8;
    #pragma unroll
    for (int j = 0; j < 8; ++j) {
        const int k = k0 + j;
        float v = 0.f;
        if (row < M && k < Kd) v = X[(size_t)row * Kd + k];
        v8[j] = (_Float16)v;
    }
    *(half8v*)&A16[(size_t)row * 128 + k0] = v8;
}

// ---------------------------------------------------------------------------
// W conversion, all 3 layers in one launch.
// ---------------------------------------------------------------------------
struct WPtrs { const float* w[12]; };

__global__ __launch_bounds__(256) void conv_W3(WPtrs P, _Float16* __restrict__ Wt16)
{
    const int t = blockIdx.x * 256 + threadIdx.x;
    if (t >= 3 * 512 * 128) return;
    const int layer = t >> 16;
    const int r = t & 65535;
    const int n = r >> 7, k = r & 127;
    const int mtx = n >> 7, cc = n & 127;
    const int Kd = (layer == 0) ? DIN : H;
    const float* W = P.w[layer * 4 + mtx];
    const float v = (k < Kd) ? W[(size_t)k * 128 + cc] : 0.f;
    Wt16[t] = (_Float16)v;
}

// ---------------------------------------------------------------------------
// MFMA GEMM v13: ONE block = 64 A-rows x ALL 4 matrices.  512 threads
// (8 waves; wave w owns cols w*16..w*16+15 of every matrix).  A staged ONCE
// (halves the A fetch vs R17's 2 y-blocks).  LDS-staged dense epilogue
// (R17-verified swizzle).  Phases: K->EK, Q(lo4B)+V(hi4B)->QV8, S.
// ---------------------------------------------------------------------------
__device__ __forceinline__ void dense_out512(const uint2 (&ldsO)[64][32],
                                             unsigned char* __restrict__ dst,
                                             int row0, int M, int t)
{
    #pragma unroll
    for (int i = 0; i < 2; ++i) {
        const int idx = i * 512 + t;            // 0..1023
        const int rr = idx >> 4, c16 = idx & 15;
        const int ch = c16 ^ ((rr & 15) >> 1);  // physical 16B chunk
        const uint2 a = ldsO[rr][2 * ch];
        const uint2 b = ldsO[rr][2 * ch + 1];
        if (row0 + rr < M) {
            uint4 o;
            if (rr & 1) { o.x = b.x; o.y = b.y; o.z = a.x; o.w = a.y; }
            else        { o.x = a.x; o.y = a.y; o.z = b.x; o.w = b.y; }
            *(uint4*)(dst + (size_t)(row0 + rr) * 256 + c16 * 16) = o;
        }
    }
}

__device__ __forceinline__ void compute_acc16(const _Float16 (&ldsA)[2][64 * 64],
                                              const _Float16* __restrict__ Wt16,
                                              int mtx, int fr, int kq, int colbase,
                                              f32x4 (&acc)[4])
{
    #pragma unroll
    for (int step = 0; step < 4; ++step) {
        const int kg = step * 4 + kq;
        const int kh = kg >> 3, kk = kg & 7;
        half8v a[4];
        #pragma unroll
        for (int m = 0; m < 4; ++m) {
            const int ar = m * 16 + fr;
            const int slot = kk ^ (ar & 7);
            a[m] = *(const half8v*)&ldsA[kh][ar * 64 + slot * 8];
        }
        const size_t wo = (size_t)(mtx * 128 + colbase + fr) * 128 + kg * 8;
        const half8v w = *(const half8v*)&Wt16[wo];
        #pragma unroll
        for (int m = 0; m < 4; ++m)
            acc[m] = __builtin_amdgcn_mfma_f32_16x16x32_f16(w, a[m], acc[m], 0, 0, 0);
    }
}

__global__ __launch_bounds__(512) void gemm_mfma(
    const _Float16* __restrict__ A16, const _Float16* __restrict__ Wt16,
    const float* __restrict__ bias0, const float* __restrict__ bias1,
    const float* __restrict__ bias2, const float* __restrict__ bias3,
    _Float16* __restrict__ OEK, unsigned char* __restrict__ QV8,
    _Float16* __restrict__ OS, int M)
{
    __shared__ _Float16 ldsA[2][64 * 64];  // 16KB
    __shared__ uint2 ldsO[64][32];         // 16KB
    const int t = threadIdx.x;
    const int l = t & 63, w = t >> 6;      // wave 0..7
    const int row0 = blockIdx.x * 64;
    const int fr = l & 15;
    const int kq = l >> 4;
    const int colbase = w * 16;

    // ---- stage A once: 1024 granules of 16B, 2 per thread
    #pragma unroll
    for (int i = 0; i < 2; ++i) {
        const int gi = i * 512 + t;        // 0..1023
        const int kh = gi >> 9;
        const int r = (gi >> 3) & 63;
        const int j = gi & 7;
        const int slot = j ^ (r & 7);
        *(half8v*)&ldsA[kh][r * 64 + slot * 8] =
            *(const half8v*)&A16[(size_t)(row0 + r) * 128 + kh * 64 + j * 8];
    }
    __syncthreads();

    const int c0 = colbase + kq * 4;
    const int qd = (c0 >> 2) ^ fr;

    // ---- K -> EK = fp16(exp(-K))
    {
        f32x4 acc[4] = {};
        compute_acc16(ldsA, Wt16, 0, fr, kq, colbase, acc);
        const float4 bv = *(const float4*)&bias0[c0];
        #pragma unroll
        for (int m = 0; m < 4; ++m) {
            const int rl = m * 16 + fr;
            half4v o;
            o[0] = (_Float16)__expf(-(acc[m][0] + bv.x));
            o[1] = (_Float16)__expf(-(acc[m][1] + bv.y));
            o[2] = (_Float16)__expf(-(acc[m][2] + bv.z));
            o[3] = (_Float16)__expf(-(acc[m][3] + bv.w));
            ldsO[rl][qd] = *(uint2*)&o;
        }
    }
    __syncthreads();
    dense_out512(ldsO, (unsigned char*)OEK, row0, M, t);
    __syncthreads();

    // ---- Q -> EQ8 (low 4B) then V -> fp8 (high 4B), same lane/quad
    {
        f32x4 acc[4] = {};
        compute_acc16(ldsA, Wt16, 1, fr, kq, colbase, acc);
        const float4 bv = *(const float4*)&bias1[c0];
        #pragma unroll
        for (int m = 0; m < 4; ++m) {
            const int rl = m * 16 + fr;
            const float e0 = __expf(-(acc[m][0] + bv.x));
            const float e1 = __expf(-(acc[m][1] + bv.y));
            const float e2 = __expf(-(acc[m][2] + bv.z));
            const float e3 = __expf(-(acc[m][3] + bv.w));
            int p = 0;
            p = __builtin_amdgcn_cvt_pk_fp8_f32(e0, e1, p, false);
            p = __builtin_amdgcn_cvt_pk_fp8_f32(e2, e3, p, true);
            ((unsigned*)&ldsO[rl][qd])[0] = (unsigned)p;
        }
    }
    {
        f32x4 acc[4] = {};
        compute_acc16(ldsA, Wt16, 2, fr, kq, colbase, acc);
        const float4 bv = *(const float4*)&bias2[c0];
        #pragma unroll
        for (int m = 0; m < 4; ++m) {
            const int rl = m * 16 + fr;
            int p = 0;
            p = __builtin_amdgcn_cvt_pk_fp8_f32(acc[m][0] + bv.x,
                                                acc[m][1] + bv.y, p, false);
            p = __builtin_amdgcn_cvt_pk_fp8_f32(acc[m][2] + bv.z,
                                                acc[m][3] + bv.w, p, true);
            ((unsigned*)&ldsO[rl][qd])[1] = (unsigned)p;
        }
    }
    __syncthreads();
    dense_out512(ldsO, QV8, row0, M, t);
    __syncthreads();

    // ---- S (skip) fp16
    {
        f32x4 acc[4] = {};
        compute_acc16(ldsA, Wt16, 3, fr, kq, colbase, acc);
        const float4 bv = *(const float4*)&bias3[c0];
        #pragma unroll
        for (int m = 0; m < 4; ++m) {
            const int rl = m * 16 + fr;
            half4v o;
            o[0] = (_Float16)(acc[m][0] + bv.x);
            o[1] = (_Float16)(acc[m][1] + bv.y);
            o[2] = (_Float16)(acc[m][2] + bv.z);
            o[3] = (_Float16)(acc[m][3] + bv.w);
            ldsO[rl][qd] = *(uint2*)&o;
        }
    }
    __syncthreads();
    dense_out512(ldsO, (unsigned char*)OS, row0, M, t);
}

// ---------------------------------------------------------------------------
// Atomic-free CSR build (unchanged from R16)
// ---------------------------------------------------------------------------
__global__ __launch_bounds__(256) void pA_hist(const int* __restrict__ ei,
                                               int* __restrict__ ghA)
{
    __shared__ int lh[NBKT];
    const int t = threadIdx.x, b = blockIdx.x;
    if (t < NBKT) lh[t] = 0;
    __syncthreads();
    const int e0 = b * CHA;
    for (int i = t; i < CHA; i += 256)
        atomicAdd(&lh[ei[N_EDGES + e0 + i] >> 8], 1);
    __syncthreads();
    if (t < NBKT) ghA[t * NBA + b] = lh[t];
}

__global__ __launch_bounds__(1024) void pA_scan(int* __restrict__ g)
{
    __shared__ int part[1024];
    const int t = threadIdx.x;
    const int NT = NBKT * NBA;
    const int CH = 20;
    const int base = t * CH;
    int s = 0;
    for (int i = 0; i < CH; ++i) {
        const int idx = base + i;
        if (idx < NT) s += g[idx];
    }
    part[t] = s;
    __syncthreads();
    for (int d = 1; d < 1024; d <<= 1) {
        const int v = (t >= d) ? part[t - d] : 0;
        __syncthreads();
        part[t] += v;
        __syncthreads();
    }
    int run = (t == 0) ? 0 : part[t - 1];
    for (int i = 0; i < CH; ++i) {
        const int idx = base + i;
        if (idx < NT) { const int c = g[idx]; g[idx] = run; run += c; }
    }
    if (t == 1023) g[NT] = part[1023];
}

__global__ __launch_bounds__(256) void pA_scat(const int* __restrict__ ei,
                                               const int* __restrict__ gbase,
                                               unsigned int* __restrict__ ebuf)
{
    __shared__ int cur[NBKT];
    const int t = threadIdx.x, b = blockIdx.x;
    if (t < NBKT) cur[t] = gbase[t * NBA + b];
    __syncthreads();
    const int e0 = b * CHA;
    for (int i = t; i < CHA; i += 256) {
        const unsigned d = (unsigned)ei[N_EDGES + e0 + i];
        const unsigned s = (unsigned)ei[e0 + i];
        const int pos = atomicAdd(&cur[d >> 8], 1);
        ebuf[pos] = (d << 16) | s;
    }
}

__global__ __launch_bounds__(256) void pB_build(const unsigned int* __restrict__ ebuf,
                                                const int* __restrict__ gbase,
                                                int* __restrict__ off,
                                                int* __restrict__ csr)
{
    __shared__ int lh[256], sc[256];
    const int t = threadIdx.x, b = blockIdx.x;
    const int beg = gbase[b * NBA];
    const int end = gbase[(b + 1) * NBA];
    lh[t] = 0;
    __syncthreads();
    for (int i = beg + t; i < end; i += 256)
        atomicAdd(&lh[(ebuf[i] >> 16) & 255], 1);
    __syncthreads();
    const int c = lh[t];
    sc[t] = c;
    __syncthreads();
    for (int d = 1; d < 256; d <<= 1) {
        const int v = (t >= d) ? sc[t - d] : 0;
        __syncthreads();
        sc[t] += v;
        __syncthreads();
    }
    const int excl = sc[t] - c;
    const int nd = b * 256 + t;
    if (nd <= N_NODES) off[nd] = beg + excl;
    __syncthreads();
    lh[t] = beg + excl;
    __syncthreads();
    for (int i = beg + t; i < end; i += 256) {
        const unsigned p = ebuf[i];
        const int pos = atomicAdd(&lh[(p >> 16) & 255], 1);
        csr[pos] = (int)(p & 0xFFFFu);
    }
}

// ---------------------------------------------------------------------------
// CSR aggregation (unchanged): 16B QV8 gathers, fp16 EK, rcp gate.
// ---------------------------------------------------------------------------
template<int FUSE>
__global__ __launch_bounds__(256) void agg_csr(
    const _Float16* __restrict__ EKb, const unsigned char* __restrict__ QV8,
    const int* __restrict__ off, const int* __restrict__ csr_src,
    _Float16* __restrict__ hSkip, _Float16* __restrict__ A16, int Nn)
{
    const int node = blockIdx.x * 4 + (threadIdx.x >> 6);
    if (node >= Nn) return;
    const int lane = threadIdx.x & 63;
    const int grp = lane >> 4;
    const int sub = lane & 15;
    const int q = sub * 8;

    const half8v ek8 = *(const half8v*)(EKb + (size_t)node * H + q);
    float ek[8];
    #pragma unroll
    for (int i = 0; i < 8; ++i) ek[i] = (float)ek8[i];
    float acc[8] = {};

    const int begin = off[node], end = off[node + 1];
    for (int j0 = begin; j0 < end; j0 += 64) {
        const int nrem = end - j0;
        const int nk = nrem < 64 ? nrem : 64;
        const int sv = (lane < nk) ? csr_src[j0 + lane] : 0;
        #pragma unroll 4
        for (int k = 0; k < nk; k += 4) {
            const int myk = k + grp;
            const int s = __shfl(sv, myk < nk ? myk : 0);
            if (myk < nk) {
                const uint4 p = *(const uint4*)(QV8 + (size_t)s * 256 + sub * 16);
                const f32x2 ea = __builtin_amdgcn_cvt_pk_f32_fp8(p.x, false);
                const f32x2 eb = __builtin_amdgcn_cvt_pk_f32_fp8(p.x, true);
                const f32x2 va = __builtin_amdgcn_cvt_pk_f32_fp8(p.y, false);
                const f32x2 vb = __builtin_amdgcn_cvt_pk_f32_fp8(p.y, true);
                const f32x2 ec = __builtin_amdgcn_cvt_pk_f32_fp8(p.z, false);
                const f32x2 ed = __builtin_amdgcn_cvt_pk_f32_fp8(p.z, true);
                const f32x2 vc = __builtin_amdgcn_cvt_pk_f32_fp8(p.w, false);
                const f32x2 vd = __builtin_amdgcn_cvt_pk_f32_fp8(p.w, true);
                acc[0] = fmaf(va[0], __builtin_amdgcn_rcpf(fmaf(ek[0], ea[0], 1.f)), acc[0]);
                acc[1] = fmaf(va[1], __builtin_amdgcn_rcpf(fmaf(ek[1], ea[1], 1.f)), acc[1]);
                acc[2] = fmaf(vb[0], __builtin_amdgcn_rcpf(fmaf(ek[2], eb[0], 1.f)), acc[2]);
                acc[3] = fmaf(vb[1], __builtin_amdgcn_rcpf(fmaf(ek[3], eb[1], 1.f)), acc[3]);
                acc[4] = fmaf(vc[0], __builtin_amdgcn_rcpf(fmaf(ek[4], ec[0], 1.f)), acc[4]);
                acc[5] = fmaf(vc[1], __builtin_amdgcn_rcpf(fmaf(ek[5], ec[1], 1.f)), acc[5]);
                acc[6] = fmaf(vd[0], __builtin_amdgcn_rcpf(fmaf(ek[6], ed[0], 1.f)), acc[6]);
                acc[7] = fmaf(vd[1], __builtin_amdgcn_rcpf(fmaf(ek[7], ed[1], 1.f)), acc[7]);
            }
        }
    }
    #pragma unroll
    for (int i = 0; i < 8; ++i) {
        acc[i] += __shfl_xor(acc[i], 16);
        acc[i] += __shfl_xor(acc[i], 32);
    }
    if (grp == 0) {
        const half8v sk8 = *(const half8v*)(hSkip + (size_t)node * H + q);
        half8v hv;
        if (FUSE) {
            #pragma unroll
            for (int j = 0; j < 8; ++j)
                hv[j] = (_Float16)fmaxf((float)sk8[j] + acc[j], 0.f);
            *(half8v*)&A16[(size_t)node * 128 + q] = hv;
        } else {
            #pragma unroll
            for (int j = 0; j < 8; ++j)
                hv[j] = (_Float16)((float)sk8[j] + acc[j]);
            *(half8v*)&hSkip[(size_t)node * H + q] = hv;
        }
    }
}

// ---------------------------------------------------------------------------
// Pool (fp16 h) + MLP (unchanged)
// ---------------------------------------------------------------------------
__global__ __launch_bounds__(256) void gstart_kernel(const int* __restrict__ batch,
                                                     int* __restrict__ gstart, int Nn)
{
    const int n = blockIdx.x * 256 + threadIdx.x;
    if (n >= Nn) return;
    const int b = batch[n];
    const int bp = (n == 0) ? -1 : batch[n - 1];
    for (int g = bp + 1; g <= b; ++g) gstart[g] = n;
    if (n == Nn - 1)
        for (int g = b + 1; g <= N_GRAPHS; ++g) gstart[g] = Nn;
}

__global__ __launch_bounds__(128) void pool_seg(const _Float16* __restrict__ h,
                                                const int* __restrict__ gstart,
                                                float* __restrict__ hg)
{
    const int g = blockIdx.x;
    const int part = blockIdx.y;
    const int t = threadIdx.x;
    const int b0 = gstart[g], b1 = gstart[g + 1];
    float acc = 0.f;
    for (int n = b0 + part; n < b1; n += 4) acc += (float)h[(size_t)n * H + t];
    atomicAdd(&hg[(size_t)g * H + t], acc);
}

__global__ __launch_bounds__(64) void mlp_kernel(
    const float* __restrict__ hg,
    const float* __restrict__ W4, const float* __restrict__ b4,
    const float* __restrict__ W5, const float* __restrict__ b5,
    float* __restrict__ out)
{
    const int g = blockIdx.x;
    const int c = threadIdx.x;
    __shared__ float hrow[H];
    for (int k = c; k < H; k += 64) hrow[k] = hg[(size_t)g * H + k];
    __syncthreads();
    float s = b4[c];
    #pragma unroll 8
    for (int k = 0; k < H; ++k) s += hrow[k] * W4[(size_t)k * 64 + c];
    s = fmaxf(s, 0.f) * W5[c];
    #pragma unroll
    for (int off = 32; off > 0; off >>= 1) s += __shfl_down(s, off);
    if (c == 0) out[g] = 1.f / (1.f + __expf(-(s + b5[0])));
}

// ---------------------------------------------------------------------------
extern "C" void kernel_launch(void* const* d_in, const int* in_sizes, int n_in,
                              void* d_out, int out_size, void* d_ws, size_t ws_size,
                              hipStream_t stream)
{
    const float* x = (const float*)d_in[0];
    const float *Wk[3], *bk[3], *Wq[3], *bq[3], *Wv[3], *bv[3], *Wsk[3], *bs[3];
    for (int l = 0; l < 3; ++l) {
        const int base = 2 + l * 8;
        Wk[l]  = (const float*)d_in[base + 0]; bk[l] = (const float*)d_in[base + 1];
        Wq[l]  = (const float*)d_in[base + 2]; bq[l] = (const float*)d_in[base + 3];
        Wv[l]  = (const float*)d_in[base + 4]; bv[l] = (const float*)d_in[base + 5];
        Wsk[l] = (const float*)d_in[base + 6]; bs[l] = (const float*)d_in[base + 7];
    }
    const float* W4 = (const float*)d_in[26];
    const float* b4 = (const float*)d_in[27];
    const float* W5 = (const float*)d_in[28];
    const float* b5 = (const float*)d_in[29];
    const int* ei    = (const int*)d_in[30];
    const int* batch = (const int*)d_in[31];
    float* out = (float*)d_out;

    const size_t NH = (size_t)N_NODES * H;
    const size_t AH = (size_t)MP * 128;
    const size_t WH3 = (size_t)3 * 512 * 128;
    _Float16*      EKb  = (_Float16*)d_ws;                    // NH halfs
    _Float16*      hbuf = EKb + NH;                           // NH halfs
    unsigned char* QV8  = (unsigned char*)(hbuf + NH);        // 2*NH bytes
    _Float16*      A16  = (_Float16*)(QV8 + 2 * NH);          // AH halfs
    _Float16*      Wt16 = A16 + AH;                           // WH3 halfs
    float*         hg   = (float*)(Wt16 + WH3);               // G*H (zeroed)
    int*           off  = (int*)(hg + (size_t)N_GRAPHS * H);  // N+1
    int*           csr  = off + (N_NODES + 1);                // E
    unsigned int*  ebuf = (unsigned int*)(csr + N_EDGES);     // E
    int*           ghA  = (int*)(ebuf + N_EDGES);             // NBKT*NBA+1
    int*           gst  = ghA + (NBKT * NBA + 1);             // G+1
    const size_t need = (size_t)N_GRAPHS * H * sizeof(float)
                      + 2 * NH * sizeof(unsigned char)
                      + (2 * NH + AH + WH3) * sizeof(_Float16)
                      + (size_t)(N_NODES + 1 + 2 * N_EDGES + NBKT * NBA + 1
                                 + N_GRAPHS + 1) * sizeof(int);
    if (ws_size < need) return;

    const int ablk = (N_NODES + 3) / 4;
    const int nblk = (N_NODES + 255) / 256;
    const int cablk = (MP * 16) / 256;
    const int ggrid = MP / 64;           // 782 blocks x 512 threads
    const dim3 pgrid(N_GRAPHS, 4);

    // ---- memset: hg only
    hipMemsetAsync(hg, 0, (size_t)N_GRAPHS * H * sizeof(float), stream);

    // ---- atomic-free CSR build + graph segments + weight conversion
    pA_hist<<<NBA, 256, 0, stream>>>(ei, ghA);
    pA_scan<<<1, 1024, 0, stream>>>(ghA);
    pA_scat<<<NBA, 256, 0, stream>>>(ei, ghA, ebuf);
    pB_build<<<NBKT, 256, 0, stream>>>(ebuf, ghA, off, csr);
    gstart_kernel<<<nblk, 256, 0, stream>>>(batch, gst, N_NODES);
    WPtrs wp;
    for (int l = 0; l < 3; ++l) {
        wp.w[l * 4 + 0] = Wk[l];
        wp.w[l * 4 + 1] = Wq[l];
        wp.w[l * 4 + 2] = Wv[l];
        wp.w[l * 4 + 3] = Wsk[l];
    }
    conv_W3<<<768, 256, 0, stream>>>(wp, Wt16);

    // ---- Layer 1
    conv_A<<<cablk, 256, 0, stream>>>(x, N_NODES, DIN, A16);
    gemm_mfma<<<ggrid, 512, 0, stream>>>(A16, Wt16,
        bk[0], bq[0], bv[0], bs[0], EKb, QV8, hbuf, N_NODES);
    agg_csr<1><<<ablk, 256, 0, stream>>>(EKb, QV8, off, csr, hbuf, A16, N_NODES);

    // ---- Layer 2
    gemm_mfma<<<ggrid, 512, 0, stream>>>(A16, Wt16 + 512 * 128,
        bk[1], bq[1], bv[1], bs[1], EKb, QV8, hbuf, N_NODES);
    agg_csr<1><<<ablk, 256, 0, stream>>>(EKb, QV8, off, csr, hbuf, A16, N_NODES);

    // ---- Layer 3
    gemm_mfma<<<ggrid, 512, 0, stream>>>(A16, Wt16 + 1024 * 128,
        bk[2], bq[2], bv[2], bs[2], EKb, QV8, hbuf, N_NODES);
    agg_csr<0><<<ablk, 256, 0, stream>>>(EKb, QV8, off, csr, hbuf, A16, N_NODES);

    // ---- Pool + MLP
    pool_seg<<<pgrid, 128, 0, stream>>>(hbuf, gst, hg);
    mlp_kernel<<<N_GRAPHS, 64, 0, stream>>>(hg, W4, b4, W5, b5, out);
}